// Round 12
// baseline (1166.219 us; speedup 1.0000x reference)
//
#include <hip/hip_runtime.h>

#define DI __device__ __forceinline__

namespace {

constexpr int kL  = 2048;
constexpr int kB  = 4;
constexpr int kE  = 512;
constexpr int kHD = 64;
constexpr int kFF = 2048;
constexpr int kNE = 5;
constexpr int kT  = 8192;   // kL * kB tokens
constexpr int kCAP = 4;

using bf16x8 = __attribute__((ext_vector_type(8))) short;
using f32x4  = __attribute__((ext_vector_type(4))) float;

DI float bf2f(unsigned short u) { return __uint_as_float(((unsigned)u) << 16); }
DI unsigned short f2bf(float f) {
  unsigned u = __float_as_uint(f);
  u = u + 0x7FFFu + ((u >> 16) & 1u);
  return (unsigned short)(u >> 16);
}

DI unsigned rotl(unsigned v, int d) { return (v << d) | (v >> (32 - d)); }

// JAX threefry2x32 with key = PRNGKey(42) = (0, 42), 20 rounds.
DI void threefry(unsigned& x0, unsigned& x1) {
  const unsigned K1 = 0u, K2 = 42u, K3 = 0x1BD11BDAu ^ 0u ^ 42u;
  x0 += K1; x1 += K2;
  x0 += x1; x1 = rotl(x1, 13); x1 ^= x0;
  x0 += x1; x1 = rotl(x1, 15); x1 ^= x0;
  x0 += x1; x1 = rotl(x1, 26); x1 ^= x0;
  x0 += x1; x1 = rotl(x1,  6); x1 ^= x0;
  x0 += K2; x1 += K3 + 1u;
  x0 += x1; x1 = rotl(x1, 17); x1 ^= x0;
  x0 += x1; x1 = rotl(x1, 29); x1 ^= x0;
  x0 += x1; x1 = rotl(x1, 16); x1 ^= x0;
  x0 += x1; x1 = rotl(x1, 24); x1 ^= x0;
  x0 += K3; x1 += K1 + 2u;
  x0 += x1; x1 = rotl(x1, 13); x1 ^= x0;
  x0 += x1; x1 = rotl(x1, 15); x1 ^= x0;
  x0 += x1; x1 = rotl(x1, 26); x1 ^= x0;
  x0 += x1; x1 = rotl(x1,  6); x1 ^= x0;
  x0 += K1; x1 += K2 + 3u;
  x0 += x1; x1 = rotl(x1, 17); x1 ^= x0;
  x0 += x1; x1 = rotl(x1, 29); x1 ^= x0;
  x0 += x1; x1 = rotl(x1, 16); x1 ^= x0;
  x0 += x1; x1 = rotl(x1, 24); x1 ^= x0;
  x0 += K2; x1 += K3 + 4u;
  x0 += x1; x1 = rotl(x1, 13); x1 ^= x0;
  x0 += x1; x1 = rotl(x1, 15); x1 ^= x0;
  x0 += x1; x1 = rotl(x1, 26); x1 ^= x0;
  x0 += x1; x1 = rotl(x1,  6); x1 ^= x0;
  x0 += K3; x1 += K1 + 5u;
}

// ---------------- f32 -> bf16 bulk convert -----------------------------------
__global__ __launch_bounds__(256) void f2bf_kernel(
    const float* __restrict__ src, unsigned short* __restrict__ dst, int n4) {
  int i = blockIdx.x * blockDim.x + threadIdx.x;
  if (i >= n4) return;
  float4 v = ((const float4*)src)[i];
  ushort4 u;
  u.x = f2bf(v.x); u.y = f2bf(v.y); u.z = f2bf(v.z); u.w = f2bf(v.w);
  ((ushort4*)dst)[i] = u;
}

// ---------------- LayerNorm (one row per block, 256 threads, E=512) -----------
__global__ __launch_bounds__(256) void ln_kernel(
    const float* __restrict__ x, const float* __restrict__ w,
    const float* __restrict__ b, float* __restrict__ out) {
  int row = blockIdx.x;
  const float* xr = x + (size_t)row * kE;
  int t = threadIdx.x;
  float2 v = *(const float2*)(xr + t * 2);
  __shared__ float red[4];
  float s = v.x + v.y;
  #pragma unroll
  for (int m = 32; m; m >>= 1) s += __shfl_xor(s, m);
  if ((t & 63) == 0) red[t >> 6] = s;
  __syncthreads();
  float mu = (red[0] + red[1] + red[2] + red[3]) * (1.0f / kE);
  float dx = v.x - mu, dy = v.y - mu;
  float q = dx * dx + dy * dy;
  #pragma unroll
  for (int m = 32; m; m >>= 1) q += __shfl_xor(q, m);
  __syncthreads();
  if ((t & 63) == 0) red[t >> 6] = q;
  __syncthreads();
  float var = (red[0] + red[1] + red[2] + red[3]) * (1.0f / kE);
  float inv = 1.0f / sqrtf(var + 1e-5f);
  float2 o;
  o.x = dx * inv * w[t * 2]     + b[t * 2];
  o.y = dy * inv * w[t * 2 + 1] + b[t * 2 + 1];
  *(float2*)(out + (size_t)row * kE + t * 2) = o;
}

// ---------------- 128x128 f32 GEMM, BT=1 (C=A*B^T), non-MOE ------------------
// XCD-swizzled, double-buffered LDS (1 barrier / K-step), pad 132 (2-way banks).
template <int BIAS, int RES>
__global__ __launch_bounds__(256) void gemm_kernel(
    const float* __restrict__ Ap, const float* __restrict__ Bp,
    const float* __restrict__ biasp, const float* __restrict__ Rp,
    float* __restrict__ Cp, int M, int N, int K) {
  __shared__ float As[2][16][132];
  __shared__ float Bs[2][16][132];

  int nwg = gridDim.x * gridDim.y;
  int bid = blockIdx.y * gridDim.x + blockIdx.x;
  int swz = (bid & 7) * (nwg >> 3) + (bid >> 3);
  int wx = swz % gridDim.x, wy = swz / gridDim.x;

  const int m0 = wy * 128;
  const int n0 = wx * 128;
  const int t = threadIdx.x;
  const int tx = t & 15, ty = t >> 4;

  const int ar = t >> 2;         // 0..63
  const int ak = (t & 3) * 4;    // k offset 0/4/8/12
  size_t arow0 = (size_t)(m0 + ar) * K + ak;
  size_t arow1 = (size_t)(m0 + ar + 64) * K + ak;
  const int b_r = t >> 2, b_o = (t & 3) * 4;

  float acc[8][8];
  #pragma unroll
  for (int i = 0; i < 8; ++i)
    #pragma unroll
    for (int j = 0; j < 8; ++j) acc[i][j] = 0.0f;

  float4 v0r, v1r, w0, w1v;
  auto load_tile = [&](int k0) {
    v0r = *(const float4*)(Ap + arow0 + k0);
    v1r = *(const float4*)(Ap + arow1 + k0);
    w0  = *(const float4*)(Bp + (size_t)(n0 + b_r) * K + k0 + b_o);
    w1v = *(const float4*)(Bp + (size_t)(n0 + b_r + 64) * K + k0 + b_o);
  };
  load_tile(0);

  for (int k0 = 0; k0 < K; k0 += 16) {
    const int bf = (k0 >> 4) & 1;
    As[bf][ak+0][ar] = v0r.x; As[bf][ak+1][ar] = v0r.y;
    As[bf][ak+2][ar] = v0r.z; As[bf][ak+3][ar] = v0r.w;
    As[bf][ak+0][ar+64] = v1r.x; As[bf][ak+1][ar+64] = v1r.y;
    As[bf][ak+2][ar+64] = v1r.z; As[bf][ak+3][ar+64] = v1r.w;
    Bs[bf][b_o+0][b_r] = w0.x; Bs[bf][b_o+1][b_r] = w0.y;
    Bs[bf][b_o+2][b_r] = w0.z; Bs[bf][b_o+3][b_r] = w0.w;
    Bs[bf][b_o+0][b_r+64] = w1v.x; Bs[bf][b_o+1][b_r+64] = w1v.y;
    Bs[bf][b_o+2][b_r+64] = w1v.z; Bs[bf][b_o+3][b_r+64] = w1v.w;
    __syncthreads();
    if (k0 + 16 < K) load_tile(k0 + 16);
    #pragma unroll
    for (int kk = 0; kk < 16; ++kk) {
      float av[8], bv[8];
      *(float4*)&av[0] = *(const float4*)&As[bf][kk][ty * 8];
      *(float4*)&av[4] = *(const float4*)&As[bf][kk][ty * 8 + 4];
      *(float4*)&bv[0] = *(const float4*)&Bs[bf][kk][tx * 4];
      *(float4*)&bv[4] = *(const float4*)&Bs[bf][kk][tx * 4 + 64];
      #pragma unroll
      for (int i = 0; i < 8; ++i)
        #pragma unroll
        for (int j = 0; j < 8; ++j)
          acc[i][j] = fmaf(av[i], bv[j], acc[i][j]);
    }
  }

  #pragma unroll
  for (int i = 0; i < 8; ++i) {
    int rloc = m0 + ty * 8 + i;
    size_t crow = (size_t)rloc * N;
    #pragma unroll
    for (int half = 0; half < 2; ++half) {
      int c = n0 + half * 64 + tx * 4;
      float v[4];
      #pragma unroll
      for (int j = 0; j < 4; ++j) {
        v[j] = acc[i][half * 4 + j];
        if (BIAS) v[j] += biasp[c + j];
        if (RES)  v[j] += Rp[crow + c + j];
      }
      *(float4*)(Cp + crow + c) = make_float4(v[0], v[1], v[2], v[3]);
    }
  }
}

// ---------------- MoE bf16 MFMA GEMM (unchanged from r11) --------------------
template <int GATHER, int RELU, int K, int N>
__global__ __launch_bounds__(256) void moe_mfma_kernel(
    const unsigned short* __restrict__ Abf, const unsigned short* __restrict__ Bbf,
    unsigned short* __restrict__ Cbf,
    const int* __restrict__ gatherp, const int* __restrict__ cntp,
    const int* __restrict__ basep) {
  __shared__ unsigned short As[128][40];   // [m][k] pad 32->40
  __shared__ unsigned short Bs[128][40];   // [n][k] transposed

  const int e = blockIdx.z;
  const int M = cntp[e];
  const int rowOff = basep[e];
  if ((int)blockIdx.y * 128 >= M) return;
  const unsigned short* Bg = Bbf + (size_t)e * K * N;
  const int m0 = blockIdx.y * 128;
  const int n0 = blockIdx.x * 128;
  const int t = threadIdx.x;
  const int lane = t & 63, w = t >> 6;
  const int wm = w >> 1, wn = w & 1;

  const int ar = t >> 1, ah = t & 1;
  size_t abase;
  {
    int r = m0 + ar;
    int mm = M - 1; r = r < mm ? r : mm;
    if (GATHER) r = gatherp[rowOff + r];
    else        r += rowOff;
    abase = (size_t)r * K;
  }
  const int bk = t >> 3, bn = (t & 7) * 16;

  f32x4 acc[4][4];
  #pragma unroll
  for (int i = 0; i < 4; ++i)
    #pragma unroll
    for (int j = 0; j < 4; ++j)
      acc[i][j] = (f32x4){0.f, 0.f, 0.f, 0.f};

  uint4 aR0, aR1, bR0, bR1;
  auto gload = [&](int k0) {
    aR0 = *(const uint4*)(Abf + abase + k0 + ah * 16);
    aR1 = *(const uint4*)(Abf + abase + k0 + ah * 16 + 8);
    bR0 = *(const uint4*)(Bg + (size_t)(k0 + bk) * N + n0 + bn);
    bR1 = *(const uint4*)(Bg + (size_t)(k0 + bk) * N + n0 + bn + 8);
  };
  gload(0);

  const int kg = (lane >> 4) * 8;
  const int mr = lane & 15;

  for (int k0 = 0; k0 < K; k0 += 32) {
    __syncthreads();
    *(uint4*)&As[ar][ah * 16]     = aR0;
    *(uint4*)&As[ar][ah * 16 + 8] = aR1;
    {
      unsigned short tmp[16];
      *(uint4*)tmp       = bR0;
      *(uint4*)(tmp + 8) = bR1;
      #pragma unroll
      for (int j = 0; j < 16; ++j) Bs[bn + j][bk] = tmp[j];
    }
    __syncthreads();
    if (k0 + 32 < K) gload(k0 + 32);

    bf16x8 af[4], bfr[4];
    #pragma unroll
    for (int i = 0; i < 4; ++i)
      af[i] = *(const bf16x8*)&As[wm * 64 + i * 16 + mr][kg];
    #pragma unroll
    for (int j = 0; j < 4; ++j)
      bfr[j] = *(const bf16x8*)&Bs[wn * 64 + j * 16 + mr][kg];
    #pragma unroll
    for (int i = 0; i < 4; ++i)
      #pragma unroll
      for (int j = 0; j < 4; ++j)
        acc[i][j] = __builtin_amdgcn_mfma_f32_16x16x32_bf16(
            af[i], bfr[j], acc[i][j], 0, 0, 0);
  }

  const int lr4 = (lane >> 4) * 4;
  const int lc = lane & 15;
  #pragma unroll
  for (int i = 0; i < 4; ++i)
    #pragma unroll
    for (int r = 0; r < 4; ++r) {
      int row = m0 + wm * 64 + i * 16 + lr4 + r;
      if (row >= M) continue;
      size_t crow = (size_t)(row + rowOff) * N;
      #pragma unroll
      for (int j = 0; j < 4; ++j) {
        float v = acc[i][j][r];
        if (RELU) v = v > 0.f ? v : 0.f;
        Cbf[crow + n0 + wn * 64 + j * 16 + lc] = f2bf(v);
      }
    }
}

// ---------------- Flash attention, f32, hd=64 --------------------------------
// 4x16KB swizzled flat LDS buffers (no aliasing) -> 3 barriers/iter.
// 16B-group XOR swizzle keeps float4 alignment; staging 2-way, P at floor.
DI int swzA(int d, int r) {       // d-major (Q^T, K^T): elem (d, r)
  return d * 64 + ((((r >> 2) ^ (d >> 2)) & 15) << 2) + (r & 3);
}
DI int swzB(int r, int d) {       // r-major (V, P): elem (r, d)
  return r * 64 + ((((d >> 2) ^ r) & 15) << 2) + (d & 3);
}

__global__ __launch_bounds__(256) void flash_kernel(
    const float* __restrict__ qkv, float* __restrict__ attn_out) {
  __shared__ float QsT[64 * 64];
  __shared__ float KsT[64 * 64];
  __shared__ float Vs[64 * 64];
  __shared__ float Ps[64 * 64];

  int bid = blockIdx.y * 32 + blockIdx.x;   // grid (32, 32)
  int swz = (bid & 7) * 128 + (bid >> 3);
  const int bh = swz >> 5;
  const int qt = swz & 31;
  const int b = bh >> 3, h = bh & 7;
  const int t = threadIdx.x;
  const int tx = t & 15, ty = t >> 4;
  const int lr = t >> 2;
  const int dbase = (t & 3) * 16;

  {
    int l = qt * 64 + lr;
    const float* qrow = qkv + ((size_t)(l * kB + b)) * (3 * kE) + h * kHD;
    #pragma unroll
    for (int j = 0; j < 4; ++j) {
      float4 v = *(const float4*)(qrow + dbase + 4 * j);
      int d = dbase + 4 * j;
      QsT[swzA(d + 0, lr)] = v.x * 0.125f;
      QsT[swzA(d + 1, lr)] = v.y * 0.125f;
      QsT[swzA(d + 2, lr)] = v.z * 0.125f;
      QsT[swzA(d + 3, lr)] = v.w * 0.125f;
    }
  }

  float m_i[4], l_i[4], Oa[4][4];
  #pragma unroll
  for (int i = 0; i < 4; ++i) {
    m_i[i] = -1e30f; l_i[i] = 0.f;
    #pragma unroll
    for (int j = 0; j < 4; ++j) Oa[i][j] = 0.f;
  }

  float4 kreg[4], vreg[4];
  {
    const float* kro = qkv + ((size_t)(lr * kB + b)) * (3 * kE) + kE + h * kHD;
    const float* vro = kro + kE;
    #pragma unroll
    for (int j = 0; j < 4; ++j) {
      kreg[j] = *(const float4*)(kro + dbase + 4 * j);
      vreg[j] = *(const float4*)(vro + dbase + 4 * j);
    }
  }

  for (int kt = 0; kt < 32; ++kt) {
    __syncthreads();   // prev iteration's PV reads (and Q staging at kt=0) done
    #pragma unroll
    for (int j = 0; j < 4; ++j) {
      int d = dbase + 4 * j;
      KsT[swzA(d + 0, lr)] = kreg[j].x;
      KsT[swzA(d + 1, lr)] = kreg[j].y;
      KsT[swzA(d + 2, lr)] = kreg[j].z;
      KsT[swzA(d + 3, lr)] = kreg[j].w;
      *(float4*)&Vs[swzB(lr, d)] = vreg[j];
    }
    __syncthreads();   // staging visible
    if (kt + 1 < 32) {
      int l = (kt + 1) * 64 + lr;
      const float* kro = qkv + ((size_t)(l * kB + b)) * (3 * kE) + kE + h * kHD;
      const float* vro = kro + kE;
      #pragma unroll
      for (int j = 0; j < 4; ++j) {
        kreg[j] = *(const float4*)(kro + dbase + 4 * j);
        vreg[j] = *(const float4*)(vro + dbase + 4 * j);
      }
    }

    float S[4][4];
    #pragma unroll
    for (int i = 0; i < 4; ++i)
      #pragma unroll
      for (int j = 0; j < 4; ++j) S[i][j] = 0.f;
    #pragma unroll 8
    for (int d = 0; d < 64; ++d) {
      float4 qv = *(const float4*)&QsT[swzA(d, ty * 4)];
      float4 kv = *(const float4*)&KsT[swzA(d, tx * 4)];
      float qa[4] = {qv.x, qv.y, qv.z, qv.w};
      float ka[4] = {kv.x, kv.y, kv.z, kv.w};
      #pragma unroll
      for (int i = 0; i < 4; ++i)
        #pragma unroll
        for (int j = 0; j < 4; ++j) S[i][j] = fmaf(qa[i], ka[j], S[i][j]);
    }

    float alpha[4];
    #pragma unroll
    for (int i = 0; i < 4; ++i) {
      float tm = fmaxf(fmaxf(S[i][0], S[i][1]), fmaxf(S[i][2], S[i][3]));
      #pragma unroll
      for (int m = 1; m < 16; m <<= 1) tm = fmaxf(tm, __shfl_xor(tm, m));
      float mn = fmaxf(m_i[i], tm);
      alpha[i] = __expf(m_i[i] - mn);
      m_i[i] = mn;
      float rs = 0.f;
      #pragma unroll
      for (int j = 0; j < 4; ++j) { S[i][j] = __expf(S[i][j] - mn); rs += S[i][j]; }
      #pragma unroll
      for (int m = 1; m < 16; m <<= 1) rs += __shfl_xor(rs, m);
      l_i[i] = l_i[i] * alpha[i] + rs;
    }
    // P write: row-major float4 (bandwidth-floor)
    #pragma unroll
    for (int i = 0; i < 4; ++i)
      *(float4*)&Ps[swzB(ty * 4 + i, tx * 4)] =
          make_float4(S[i][0], S[i][1], S[i][2], S[i][3]);
    __syncthreads();   // P visible

    #pragma unroll
    for (int i = 0; i < 4; ++i)
      #pragma unroll
      for (int j = 0; j < 4; ++j) Oa[i][j] *= alpha[i];
    #pragma unroll 4
    for (int kvc = 0; kvc < 16; ++kvc) {
      float pvw[4][4];
      #pragma unroll
      for (int i = 0; i < 4; ++i)
        *(float4*)&pvw[i][0] = *(const float4*)&Ps[swzB(ty * 4 + i, kvc * 4)];
      #pragma unroll
      for (int q = 0; q < 4; ++q) {
        float4 vv = *(const float4*)&Vs[swzB(kvc * 4 + q, tx * 4)];
        float va[4] = {vv.x, vv.y, vv.z, vv.w};
        #pragma unroll
        for (int i = 0; i < 4; ++i)
          #pragma unroll
          for (int j = 0; j < 4; ++j)
            Oa[i][j] = fmaf(pvw[i][q], va[j], Oa[i][j]);
      }
    }
  }

  #pragma unroll
  for (int i = 0; i < 4; ++i) {
    int l = qt * 64 + ty * 4 + i;
    float inv = 1.0f / l_i[i];
    float4 o = make_float4(Oa[i][0]*inv, Oa[i][1]*inv, Oa[i][2]*inv, Oa[i][3]*inv);
    *(float4*)(attn_out + ((size_t)(l * kB + b)) * kE + h * kHD + tx * 4) = o;
  }
}

// ---------------- Gating: logits, softmax, top2, partitionable-XOR threefry --
__global__ __launch_bounds__(256) void gating_kernel(
    const float* __restrict__ h2, const float* __restrict__ wg,
    int* __restrict__ e1, int* __restrict__ e2,
    float* __restrict__ g1, float* __restrict__ g2,
    int* __restrict__ keepr) {
  __shared__ float swg[kE * kNE];
  for (int i = threadIdx.x; i < kE * kNE; i += 256) swg[i] = wg[i];
  __syncthreads();
  int w = threadIdx.x >> 6, lane = threadIdx.x & 63;
  int tok = blockIdx.x * 4 + w;
  const float* xr = h2 + (size_t)tok * kE;
  float a0=0,a1=0,a2=0,a3=0,a4=0;
  for (int d = lane; d < kE; d += 64) {
    float xv = xr[d];
    a0 = fmaf(xv, swg[d*5+0], a0);
    a1 = fmaf(xv, swg[d*5+1], a1);
    a2 = fmaf(xv, swg[d*5+2], a2);
    a3 = fmaf(xv, swg[d*5+3], a3);
    a4 = fmaf(xv, swg[d*5+4], a4);
  }
  #pragma unroll
  for (int m = 32; m; m >>= 1) {
    a0 += __shfl_xor(a0, m); a1 += __shfl_xor(a1, m); a2 += __shfl_xor(a2, m);
    a3 += __shfl_xor(a3, m); a4 += __shfl_xor(a4, m);
  }
  if (lane == 0) {
    float lg[5] = {a0, a1, a2, a3, a4};
    float mx = lg[0];
    #pragma unroll
    for (int e = 1; e < 5; ++e) mx = fmaxf(mx, lg[e]);
    float ex[5], ssum = 0.f;
    #pragma unroll
    for (int e = 0; e < 5; ++e) { ex[e] = expf(lg[e] - mx); ssum += ex[e]; }
    float raw[5];
    #pragma unroll
    for (int e = 0; e < 5; ++e) raw[e] = ex[e] / ssum;
    int i1 = 0; float v1 = raw[0];
    #pragma unroll
    for (int e = 1; e < 5; ++e) if (raw[e] > v1) { v1 = raw[e]; i1 = e; }
    int i2 = 0; float v2 = -1.f;
    #pragma unroll
    for (int e = 0; e < 5; ++e) if (e != i1 && raw[e] > v2) { v2 = raw[e]; i2 = e; }
    float denom = v1 + v2 + 1e-9f;
    float G1 = v1 / denom, G2 = v2 / denom;
    // JAX partitionable threefry, 32-bit: bits = x0 ^ x1, counter (0, tok).
    unsigned x0 = 0u, x1 = (unsigned)tok;
    threefry(x0, x1);
    unsigned bits = x0 ^ x1;
    float u = __uint_as_float((bits >> 9) | 0x3F800000u) - 1.0f;
    int kr = (u < G2 / 0.2f) ? 1 : 0;
    e1[tok] = i1; e2[tok] = i2; g1[tok] = G1; g2[tok] = G2; keepr[tok] = kr;
  }
}

// ---------------- Per-group plan: positions + capacity -----------------------
__global__ __launch_bounds__(256) void plan_kernel(
    const int* __restrict__ e1, const int* __restrict__ e2,
    const int* __restrict__ keepr,
    int* __restrict__ slot1, int* __restrict__ slot2, int* __restrict__ tot) {
  int l = blockIdx.x * blockDim.x + threadIdx.x;
  if (l >= kL) return;
  int base = l * 4;
  int e1v[4], e2v[4], kr[4];
  #pragma unroll
  for (int n = 0; n < 4; ++n) {
    e1v[n] = e1[base + n]; e2v[n] = e2[base + n]; kr[n] = keepr[base + n];
  }
  int c1[5] = {0,0,0,0,0};
  int s1[4];
  #pragma unroll
  for (int n = 0; n < 4; ++n) {
    int e = e1v[n];
    int p = 0;
    #pragma unroll
    for (int q = 0; q < 5; ++q) if (q == e) p = c1[q];
    s1[n] = p;
    #pragma unroll
    for (int q = 0; q < 5; ++q) c1[q] += (q == e);
  }
  int run[5] = {0,0,0,0,0}, adm[5] = {0,0,0,0,0};
  int s2[4];
  #pragma unroll
  for (int n = 0; n < 4; ++n) {
    s2[n] = -1;
    if (kr[n]) {
      int e = e2v[n];
      int p = 0;
      #pragma unroll
      for (int q = 0; q < 5; ++q) if (q == e) p = c1[q] + run[q];
      if (p < kCAP) {
        s2[n] = p;
        #pragma unroll
        for (int q = 0; q < 5; ++q) adm[q] += (q == e);
      }
      #pragma unroll
      for (int q = 0; q < 5; ++q) run[q] += (q == e);
    }
  }
  #pragma unroll
  for (int n = 0; n < 4; ++n) { slot1[base + n] = s1[n]; slot2[base + n] = s2[n]; }
  #pragma unroll
  for (int q = 0; q < 5; ++q) tot[l * kNE + q] = c1[q] + adm[q];
}

// ---------------- Per-expert exclusive scan of group totals ------------------
__global__ __launch_bounds__(256) void scan_kernel(
    const int* __restrict__ tot, int* __restrict__ gbase, int* __restrict__ cnt) {
  int e = blockIdx.x;       // one block per expert
  int t = threadIdx.x;
  int lane = t & 63, w = t >> 6;
  __shared__ int wsum[4];
  __shared__ int carry;
  if (t == 0) carry = 0;
  __syncthreads();
  for (int chunk = 0; chunk < kL / 256; ++chunk) {
    int g = chunk * 256 + t;
    int v = tot[g * kNE + e];
    int inc = v;
    #pragma unroll
    for (int off = 1; off < 64; off <<= 1) {
      int u = __shfl_up(inc, off);
      if (lane >= off) inc += u;
    }
    if (lane == 63) wsum[w] = inc;
    __syncthreads();
    int wb = 0;
    #pragma unroll
    for (int i = 0; i < 4; ++i) wb += (i < w) ? wsum[i] : 0;
    int total = wsum[0] + wsum[1] + wsum[2] + wsum[3];
    gbase[g * kNE + e] = carry + wb + inc - v;
    __syncthreads();
    if (t == 0) carry += total;
    __syncthreads();
  }
  if (t == 0) cnt[e] = carry;
}

__global__ void bases_kernel(const int* __restrict__ cnt, int* __restrict__ base) {
  if (threadIdx.x == 0 && blockIdx.x == 0) {
    int a = 0;
    #pragma unroll
    for (int e = 0; e < kNE; ++e) { base[e] = a; a += cnt[e]; }
  }
}

// ---------------- Row map: token -> expert-buffer rows -----------------------
__global__ __launch_bounds__(256) void rowmap_kernel(
    const int* __restrict__ e1, const int* __restrict__ e2,
    const int* __restrict__ slot1, const int* __restrict__ slot2,
    const int* __restrict__ gbase, const int* __restrict__ ebase,
    int* __restrict__ rowOf1, int* __restrict__ rowOf2,
    int* __restrict__ tokOfRow) {
  int tok = blockIdx.x * blockDim.x + threadIdx.x;
  if (tok >= kT) return;
  int l = tok >> 2;
  int a = e1[tok];
  int r1 = ebase[a] + gbase[l * kNE + a] + slot1[tok];
  rowOf1[tok] = r1;
  tokOfRow[r1] = tok;
  int s2 = slot2[tok];
  int r2 = -1;
  if (s2 >= 0) {
    int bq = e2[tok];
    r2 = ebase[bq] + gbase[l * kNE + bq] + s2;
    tokOfRow[r2] = tok;
  }
  rowOf2[tok] = r2;
}

// ---------------- Final combine: out = x_res + g1*eo[r1] + g2*eo[r2] ---------
__global__ __launch_bounds__(128) void combine_kernel(
    const float* __restrict__ xres, const unsigned short* __restrict__ eo,
    const float* __restrict__ g1, const float* __restrict__ g2,
    const int* __restrict__ rowOf1, const int* __restrict__ rowOf2,
    float* __restrict__ out) {
  int tok = blockIdx.x;
  int t = threadIdx.x;
  float4 o = *(const float4*)(xres + (size_t)tok * kE + t * 4);
  int p1 = rowOf1[tok];
  float G1 = g1[tok];
  ushort4 a = *(const ushort4*)(eo + (size_t)p1 * kE + t * 4);
  o.x += G1 * bf2f(a.x); o.y += G1 * bf2f(a.y);
  o.z += G1 * bf2f(a.z); o.w += G1 * bf2f(a.w);
  int p2 = rowOf2[tok];
  if (p2 >= 0) {
    float G2 = g2[tok];
    ushort4 c = *(const ushort4*)(eo + (size_t)p2 * kE + t * 4);
    o.x += G2 * bf2f(c.x); o.y += G2 * bf2f(c.y);
    o.z += G2 * bf2f(c.z); o.w += G2 * bf2f(c.w);
  }
  *(float4*)(out + (size_t)tok * kE + t * 4) = o;
}

}  // namespace

extern "C" void kernel_launch(void* const* d_in, const int* in_sizes, int n_in,
                              void* d_out, int out_size, void* d_ws, size_t ws_size,
                              hipStream_t stream) {
  (void)in_sizes; (void)n_in; (void)out_size;
  const float* x    = (const float*)d_in[0];
  const float* ln1w = (const float*)d_in[1];
  const float* ln1b = (const float*)d_in[2];
  const float* ln2w = (const float*)d_in[3];
  const float* ln2b = (const float*)d_in[4];
  const float* wqkv = (const float*)d_in[5];
  const float* bqkv = (const float*)d_in[6];
  const float* wo   = (const float*)d_in[7];
  const float* bo   = (const float*)d_in[8];
  const float* wg   = (const float*)d_in[9];
  const float* w1   = (const float*)d_in[10];
  const float* w2   = (const float*)d_in[11];
  float* out = (float*)d_out;

  // workspace layout (float units), 135 MB = 33,750,000 floats:
  // [0,        4194304)   xres (f32)
  // [4194304,  20971520)  hmoe bf16 (16384x2048); earlier reused as:
  //                         qkv f32 [4194304,16777216), h1 f32 [16777216,20971520)
  // [20971520, 25165824)  h2 f32 (dead after gating) -> eo bf16 (16384x512)
  // [25165824, 27262976)  h2bf (8192x512 bf16)
  // [27262976, 29884416)  w1bf (5x512x2048 bf16)
  // [29884416, 32505856)  w2bf (5x2048x512 bf16)
  // [32505856, ...)       int buffers (~111K ints)
  if (ws_size < (size_t)135000000) return;
  float* ws   = (float*)d_ws;
  float* xres = ws;
  unsigned short* hmoe = (unsigned short*)(ws + 4194304);
  float* qkv  = ws + 4194304;
  float* h1   = ws + 16777216;
  float* h2   = ws + 20971520;
  unsigned short* eobf = (unsigned short*)(ws + 20971520);
  unsigned short* h2bf = (unsigned short*)(ws + 25165824);
  unsigned short* w1bf = (unsigned short*)(ws + 27262976);
  unsigned short* w2bf = (unsigned short*)(ws + 29884416);
  int* ibuf    = (int*)(ws + 32505856);
  int* e1      = ibuf;                 // 8192
  int* e2      = e1 + kT;              // 8192
  float* g1f   = (float*)(e2 + kT);    // 8192
  float* g2f   = g1f + kT;             // 8192
  int* keepr   = (int*)(g2f + kT);     // 8192
  int* slot1   = keepr + kT;           // 8192
  int* slot2   = slot1 + kT;           // 8192
  int* rowOf1  = slot2 + kT;           // 8192
  int* rowOf2  = rowOf1 + kT;          // 8192
  int* tot     = rowOf2 + kT;          // 2048*5
  int* gbase   = tot + kL * kNE;       // 2048*5
  int* tokOfRow= gbase + kL * kNE;     // 16384
  int* cnt     = tokOfRow + 2 * kT;    // 8
  int* ebase   = cnt + 8;              // 8

  // 0. weights -> bf16
  f2bf_kernel<<<5120, 256, 0, stream>>>(w1, w1bf, kNE * kE * kFF / 4);
  f2bf_kernel<<<5120, 256, 0, stream>>>(w2, w2bf, kNE * kFF * kE / 4);
  // 1. h1 = LN1(x)
  ln_kernel<<<kT, 256, 0, stream>>>(x, ln1w, ln1b, h1);
  // 2. qkv = h1 @ Wqkv^T + b  (M=8192, N=1536, K=512)
  gemm_kernel<1,0><<<dim3(12, 64, 1), 256, 0, stream>>>(
      h1, wqkv, bqkv, nullptr, qkv, kT, 1536, kE);
  // 3. attention (f32 flash), writes attn_out into h1
  flash_kernel<<<dim3(32, 32, 1), 256, 0, stream>>>(qkv, h1);
  // 4. x_res = x + attn_out @ Wo^T + bo  (M=8192, N=512, K=512)
  gemm_kernel<1,1><<<dim3(4, 64, 1), 256, 0, stream>>>(
      h1, wo, bo, x, xres, kT, kE, kE);
  // 5. h2 = LN2(x_res)
  ln_kernel<<<kT, 256, 0, stream>>>(xres, ln2w, ln2b, h2);
  // 6. gating per token (partitionable-XOR threefry — verified r8)
  gating_kernel<<<kL, 256, 0, stream>>>(h2, wg, e1, e2, g1f, g2f, keepr);
  // 6b. h2 -> bf16 (for MFMA FF1 A operand)
  f2bf_kernel<<<4096, 256, 0, stream>>>(h2, h2bf, kT * kE / 4);
  // 7. per-group plan (positions + capacity)
  plan_kernel<<<kL / 256, 256, 0, stream>>>(e1, e2, keepr, slot1, slot2, tot);
  // 8. per-expert scan; expert bases; token->row maps
  scan_kernel<<<kNE, 256, 0, stream>>>(tot, gbase, cnt);
  bases_kernel<<<1, 32, 0, stream>>>(cnt, ebase);
  rowmap_kernel<<<kT / 256, 256, 0, stream>>>(
      e1, e2, slot1, slot2, gbase, ebase, rowOf1, rowOf2, tokOfRow);
  // 9. hmoe = relu(gather(h2bf) @ w1bf[e])  -- bf16 MFMA
  moe_mfma_kernel<1,1,kE,kFF><<<dim3(16, 64, kNE), 256, 0, stream>>>(
      h2bf, w1bf, hmoe, tokOfRow, cnt, ebase);
  // 10. eo = hmoe @ w2bf[e]  -- bf16 MFMA
  moe_mfma_kernel<0,0,kFF,kE><<<dim3(4, 64, kNE), 256, 0, stream>>>(
      hmoe, w2bf, eobf, nullptr, cnt, ebase);
  // 11. out = x_res + g1*eo[r1] + g2*eo[r2]
  combine_kernel<<<kT, 128, 0, stream>>>(
      xres, eobf, g1f, g2f, rowOf1, rowOf2, out);
}

// Round 13
// 983.301 us; speedup vs baseline: 1.1860x; 1.1860x over previous
//
#include <hip/hip_runtime.h>

#define DI __device__ __forceinline__

namespace {

constexpr int kL  = 2048;
constexpr int kB  = 4;
constexpr int kE  = 512;
constexpr int kHD = 64;
constexpr int kFF = 2048;
constexpr int kNE = 5;
constexpr int kT  = 8192;   // kL * kB tokens
constexpr int kCAP = 4;

using bf16x8 = __attribute__((ext_vector_type(8))) short;
using f32x4  = __attribute__((ext_vector_type(4))) float;

DI float bf2f(unsigned short u) { return __uint_as_float(((unsigned)u) << 16); }
DI unsigned short f2bf(float f) {
  unsigned u = __float_as_uint(f);
  u = u + 0x7FFFu + ((u >> 16) & 1u);
  return (unsigned short)(u >> 16);
}

DI unsigned rotl(unsigned v, int d) { return (v << d) | (v >> (32 - d)); }

// JAX threefry2x32 with key = PRNGKey(42) = (0, 42), 20 rounds.
DI void threefry(unsigned& x0, unsigned& x1) {
  const unsigned K1 = 0u, K2 = 42u, K3 = 0x1BD11BDAu ^ 0u ^ 42u;
  x0 += K1; x1 += K2;
  x0 += x1; x1 = rotl(x1, 13); x1 ^= x0;
  x0 += x1; x1 = rotl(x1, 15); x1 ^= x0;
  x0 += x1; x1 = rotl(x1, 26); x1 ^= x0;
  x0 += x1; x1 = rotl(x1,  6); x1 ^= x0;
  x0 += K2; x1 += K3 + 1u;
  x0 += x1; x1 = rotl(x1, 17); x1 ^= x0;
  x0 += x1; x1 = rotl(x1, 29); x1 ^= x0;
  x0 += x1; x1 = rotl(x1, 16); x1 ^= x0;
  x0 += x1; x1 = rotl(x1, 24); x1 ^= x0;
  x0 += K3; x1 += K1 + 2u;
  x0 += x1; x1 = rotl(x1, 13); x1 ^= x0;
  x0 += x1; x1 = rotl(x1, 15); x1 ^= x0;
  x0 += x1; x1 = rotl(x1, 26); x1 ^= x0;
  x0 += x1; x1 = rotl(x1,  6); x1 ^= x0;
  x0 += K1; x1 += K2 + 3u;
  x0 += x1; x1 = rotl(x1, 17); x1 ^= x0;
  x0 += x1; x1 = rotl(x1, 29); x1 ^= x0;
  x0 += x1; x1 = rotl(x1, 16); x1 ^= x0;
  x0 += x1; x1 = rotl(x1, 24); x1 ^= x0;
  x0 += K2; x1 += K3 + 4u;
  x0 += x1; x1 = rotl(x1, 13); x1 ^= x0;
  x0 += x1; x1 = rotl(x1, 15); x1 ^= x0;
  x0 += x1; x1 = rotl(x1, 26); x1 ^= x0;
  x0 += x1; x1 = rotl(x1,  6); x1 ^= x0;
  x0 += K3; x1 += K1 + 5u;
}

// ---------------- f32 -> bf16 bulk convert -----------------------------------
__global__ __launch_bounds__(256) void f2bf_kernel(
    const float* __restrict__ src, unsigned short* __restrict__ dst, int n4) {
  int i = blockIdx.x * blockDim.x + threadIdx.x;
  if (i >= n4) return;
  float4 v = ((const float4*)src)[i];
  ushort4 u;
  u.x = f2bf(v.x); u.y = f2bf(v.y); u.z = f2bf(v.z); u.w = f2bf(v.w);
  ((ushort4*)dst)[i] = u;
}

// ---------------- LayerNorm (one row per block, 256 threads, E=512) -----------
__global__ __launch_bounds__(256) void ln_kernel(
    const float* __restrict__ x, const float* __restrict__ w,
    const float* __restrict__ b, float* __restrict__ out) {
  int row = blockIdx.x;
  const float* xr = x + (size_t)row * kE;
  int t = threadIdx.x;
  float2 v = *(const float2*)(xr + t * 2);
  __shared__ float red[4];
  float s = v.x + v.y;
  #pragma unroll
  for (int m = 32; m; m >>= 1) s += __shfl_xor(s, m);
  if ((t & 63) == 0) red[t >> 6] = s;
  __syncthreads();
  float mu = (red[0] + red[1] + red[2] + red[3]) * (1.0f / kE);
  float dx = v.x - mu, dy = v.y - mu;
  float q = dx * dx + dy * dy;
  #pragma unroll
  for (int m = 32; m; m >>= 1) q += __shfl_xor(q, m);
  __syncthreads();
  if ((t & 63) == 0) red[t >> 6] = q;
  __syncthreads();
  float var = (red[0] + red[1] + red[2] + red[3]) * (1.0f / kE);
  float inv = 1.0f / sqrtf(var + 1e-5f);
  float2 o;
  o.x = dx * inv * w[t * 2]     + b[t * 2];
  o.y = dy * inv * w[t * 2 + 1] + b[t * 2 + 1];
  *(float2*)(out + (size_t)row * kE + t * 2) = o;
}

// ---------------- 128x128 f32 GEMM, BT=1 (C=A*B^T), non-MOE ------------------
template <int BIAS, int RES>
__global__ __launch_bounds__(256) void gemm_kernel(
    const float* __restrict__ Ap, const float* __restrict__ Bp,
    const float* __restrict__ biasp, const float* __restrict__ Rp,
    float* __restrict__ Cp, int M, int N, int K) {
  __shared__ float As[2][16][132];
  __shared__ float Bs[2][16][132];

  int nwg = gridDim.x * gridDim.y;
  int bid = blockIdx.y * gridDim.x + blockIdx.x;
  int swz = (bid & 7) * (nwg >> 3) + (bid >> 3);
  int wx = swz % gridDim.x, wy = swz / gridDim.x;

  const int m0 = wy * 128;
  const int n0 = wx * 128;
  const int t = threadIdx.x;
  const int tx = t & 15, ty = t >> 4;

  const int ar = t >> 2;
  const int ak = (t & 3) * 4;
  size_t arow0 = (size_t)(m0 + ar) * K + ak;
  size_t arow1 = (size_t)(m0 + ar + 64) * K + ak;
  const int b_r = t >> 2, b_o = (t & 3) * 4;

  float acc[8][8];
  #pragma unroll
  for (int i = 0; i < 8; ++i)
    #pragma unroll
    for (int j = 0; j < 8; ++j) acc[i][j] = 0.0f;

  float4 v0r, v1r, w0, w1v;
  auto load_tile = [&](int k0) {
    v0r = *(const float4*)(Ap + arow0 + k0);
    v1r = *(const float4*)(Ap + arow1 + k0);
    w0  = *(const float4*)(Bp + (size_t)(n0 + b_r) * K + k0 + b_o);
    w1v = *(const float4*)(Bp + (size_t)(n0 + b_r + 64) * K + k0 + b_o);
  };
  load_tile(0);

  for (int k0 = 0; k0 < K; k0 += 16) {
    const int bf = (k0 >> 4) & 1;
    As[bf][ak+0][ar] = v0r.x; As[bf][ak+1][ar] = v0r.y;
    As[bf][ak+2][ar] = v0r.z; As[bf][ak+3][ar] = v0r.w;
    As[bf][ak+0][ar+64] = v1r.x; As[bf][ak+1][ar+64] = v1r.y;
    As[bf][ak+2][ar+64] = v1r.z; As[bf][ak+3][ar+64] = v1r.w;
    Bs[bf][b_o+0][b_r] = w0.x; Bs[bf][b_o+1][b_r] = w0.y;
    Bs[bf][b_o+2][b_r] = w0.z; Bs[bf][b_o+3][b_r] = w0.w;
    Bs[bf][b_o+0][b_r+64] = w1v.x; Bs[bf][b_o+1][b_r+64] = w1v.y;
    Bs[bf][b_o+2][b_r+64] = w1v.z; Bs[bf][b_o+3][b_r+64] = w1v.w;
    __syncthreads();
    if (k0 + 16 < K) load_tile(k0 + 16);
    #pragma unroll
    for (int kk = 0; kk < 16; ++kk) {
      float av[8], bv[8];
      *(float4*)&av[0] = *(const float4*)&As[bf][kk][ty * 8];
      *(float4*)&av[4] = *(const float4*)&As[bf][kk][ty * 8 + 4];
      *(float4*)&bv[0] = *(const float4*)&Bs[bf][kk][tx * 4];
      *(float4*)&bv[4] = *(const float4*)&Bs[bf][kk][tx * 4 + 64];
      #pragma unroll
      for (int i = 0; i < 8; ++i)
        #pragma unroll
        for (int j = 0; j < 8; ++j)
          acc[i][j] = fmaf(av[i], bv[j], acc[i][j]);
    }
  }

  #pragma unroll
  for (int i = 0; i < 8; ++i) {
    int rloc = m0 + ty * 8 + i;
    size_t crow = (size_t)rloc * N;
    #pragma unroll
    for (int half = 0; half < 2; ++half) {
      int c = n0 + half * 64 + tx * 4;
      float v[4];
      #pragma unroll
      for (int j = 0; j < 4; ++j) {
        v[j] = acc[i][half * 4 + j];
        if (BIAS) v[j] += biasp[c + j];
        if (RES)  v[j] += Rp[crow + c + j];
      }
      *(float4*)(Cp + crow + c) = make_float4(v[0], v[1], v[2], v[3]);
    }
  }
}

// ---------------- MoE bf16 MFMA GEMM (unchanged, verified r11) ---------------
template <int GATHER, int RELU, int K, int N>
__global__ __launch_bounds__(256) void moe_mfma_kernel(
    const unsigned short* __restrict__ Abf, const unsigned short* __restrict__ Bbf,
    unsigned short* __restrict__ Cbf,
    const int* __restrict__ gatherp, const int* __restrict__ cntp,
    const int* __restrict__ basep) {
  __shared__ unsigned short As[128][40];
  __shared__ unsigned short Bs[128][40];

  const int e = blockIdx.z;
  const int M = cntp[e];
  const int rowOff = basep[e];
  if ((int)blockIdx.y * 128 >= M) return;
  const unsigned short* Bg = Bbf + (size_t)e * K * N;
  const int m0 = blockIdx.y * 128;
  const int n0 = blockIdx.x * 128;
  const int t = threadIdx.x;
  const int lane = t & 63, w = t >> 6;
  const int wm = w >> 1, wn = w & 1;

  const int ar = t >> 1, ah = t & 1;
  size_t abase;
  {
    int r = m0 + ar;
    int mm = M - 1; r = r < mm ? r : mm;
    if (GATHER) r = gatherp[rowOff + r];
    else        r += rowOff;
    abase = (size_t)r * K;
  }
  const int bk = t >> 3, bn = (t & 7) * 16;

  f32x4 acc[4][4];
  #pragma unroll
  for (int i = 0; i < 4; ++i)
    #pragma unroll
    for (int j = 0; j < 4; ++j)
      acc[i][j] = (f32x4){0.f, 0.f, 0.f, 0.f};

  uint4 aR0, aR1, bR0, bR1;
  auto gload = [&](int k0) {
    aR0 = *(const uint4*)(Abf + abase + k0 + ah * 16);
    aR1 = *(const uint4*)(Abf + abase + k0 + ah * 16 + 8);
    bR0 = *(const uint4*)(Bg + (size_t)(k0 + bk) * N + n0 + bn);
    bR1 = *(const uint4*)(Bg + (size_t)(k0 + bk) * N + n0 + bn + 8);
  };
  gload(0);

  const int kg = (lane >> 4) * 8;
  const int mr = lane & 15;

  for (int k0 = 0; k0 < K; k0 += 32) {
    __syncthreads();
    *(uint4*)&As[ar][ah * 16]     = aR0;
    *(uint4*)&As[ar][ah * 16 + 8] = aR1;
    {
      unsigned short tmp[16];
      *(uint4*)tmp       = bR0;
      *(uint4*)(tmp + 8) = bR1;
      #pragma unroll
      for (int j = 0; j < 16; ++j) Bs[bn + j][bk] = tmp[j];
    }
    __syncthreads();
    if (k0 + 32 < K) gload(k0 + 32);

    bf16x8 af[4], bfr[4];
    #pragma unroll
    for (int i = 0; i < 4; ++i)
      af[i] = *(const bf16x8*)&As[wm * 64 + i * 16 + mr][kg];
    #pragma unroll
    for (int j = 0; j < 4; ++j)
      bfr[j] = *(const bf16x8*)&Bs[wn * 64 + j * 16 + mr][kg];
    #pragma unroll
    for (int i = 0; i < 4; ++i)
      #pragma unroll
      for (int j = 0; j < 4; ++j)
        acc[i][j] = __builtin_amdgcn_mfma_f32_16x16x32_bf16(
            af[i], bfr[j], acc[i][j], 0, 0, 0);
  }

  const int lr4 = (lane >> 4) * 4;
  const int lc = lane & 15;
  #pragma unroll
  for (int i = 0; i < 4; ++i)
    #pragma unroll
    for (int r = 0; r < 4; ++r) {
      int row = m0 + wm * 64 + i * 16 + lr4 + r;
      if (row >= M) continue;
      size_t crow = (size_t)(row + rowOff) * N;
      #pragma unroll
      for (int j = 0; j < 4; ++j) {
        float v = acc[i][j][r];
        if (RELU) v = v > 0.f ? v : 0.f;
        Cbf[crow + n0 + wn * 64 + j * 16 + lc] = f2bf(v);
      }
    }
}

// ---------------- Flash attention: split-bf16 MFMA QK^T + f32 PV -------------
// Q in registers (A-frags, hi/lo). K staged hi/lo bf16 [64][72] (2-way banks).
// S = qhi*khi + qhi*klo + qlo*khi via mfma_16x16x32_bf16 (err ~1e-5, safe).
// Softmax in MFMA C-layout, wave-parallel shfl_xor reduce. PV stays f32.
// LDS ~51 KB -> 3 blocks/CU.
DI int swzB(int r, int d) {       // r-major (V, P): elem (r, d)
  return r * 64 + ((((d >> 2) ^ r) & 15) << 2) + (d & 3);
}

__global__ __launch_bounds__(256) void flash_kernel(
    const float* __restrict__ qkv, float* __restrict__ attn_out) {
  __shared__ unsigned short Khi[64][72];
  __shared__ unsigned short Klo[64][72];
  __shared__ float Vs[64 * 64];
  __shared__ float Ps[64 * 64];
  __shared__ float salpha[64];
  __shared__ float sli[64];

  int bid = blockIdx.y * 32 + blockIdx.x;   // grid (32, 32)
  int swz = (bid & 7) * 128 + (bid >> 3);
  const int bh = swz >> 5;
  const int qt = swz & 31;
  const int b = bh >> 3, h = bh & 7;
  const int t = threadIdx.x;
  const int w = t >> 6, lane = t & 63;
  const int l15 = lane & 15, l4 = lane >> 4;
  const int tx = t & 15, ty = t >> 4;
  const int lr = t >> 2;
  const int dbase = (t & 3) * 16;

  // Q A-fragments in registers, scaled 0.125, split hi/lo
  bf16x8 qhi[2], qlo[2];
  {
    int qglob = qt * 64 + w * 16 + l15;
    const float* qrow = qkv + ((size_t)(qglob * kB + b)) * (3 * kE) + h * kHD;
    #pragma unroll
    for (int ks = 0; ks < 2; ++ks) {
      int d0 = ks * 32 + l4 * 8;
      float4 v0 = *(const float4*)(qrow + d0);
      float4 v1 = *(const float4*)(qrow + d0 + 4);
      float vv[8] = {v0.x, v0.y, v0.z, v0.w, v1.x, v1.y, v1.z, v1.w};
      #pragma unroll
      for (int i = 0; i < 8; ++i) {
        float xq = vv[i] * 0.125f;
        unsigned short hi = f2bf(xq);
        qhi[ks][i] = (short)hi;
        qlo[ks][i] = (short)f2bf(xq - bf2f(hi));
      }
    }
  }

  float m_i[4], l_i[4], Oa[4][4];
  #pragma unroll
  for (int r = 0; r < 4; ++r) {
    m_i[r] = -1e30f; l_i[r] = 0.f;
    #pragma unroll
    for (int j = 0; j < 4; ++j) Oa[r][j] = 0.f;
  }

  float4 kreg[4], vreg[4];
  {
    const float* kro = qkv + ((size_t)(lr * kB + b)) * (3 * kE) + kE + h * kHD;
    const float* vro = kro + kE;
    #pragma unroll
    for (int j = 0; j < 4; ++j) {
      kreg[j] = *(const float4*)(kro + dbase + 4 * j);
      vreg[j] = *(const float4*)(vro + dbase + 4 * j);
    }
  }

  for (int kt = 0; kt < 32; ++kt) {
    __syncthreads();                 // prev PV/frag reads done
    {
      float kv16[16] = {kreg[0].x, kreg[0].y, kreg[0].z, kreg[0].w,
                        kreg[1].x, kreg[1].y, kreg[1].z, kreg[1].w,
                        kreg[2].x, kreg[2].y, kreg[2].z, kreg[2].w,
                        kreg[3].x, kreg[3].y, kreg[3].z, kreg[3].w};
      unsigned short th[16], tl[16];
      #pragma unroll
      for (int i = 0; i < 16; ++i) {
        unsigned short hi = f2bf(kv16[i]);
        th[i] = hi;
        tl[i] = f2bf(kv16[i] - bf2f(hi));
      }
      *(uint4*)&Khi[lr][dbase]     = ((uint4*)th)[0];
      *(uint4*)&Khi[lr][dbase + 8] = ((uint4*)th)[1];
      *(uint4*)&Klo[lr][dbase]     = ((uint4*)tl)[0];
      *(uint4*)&Klo[lr][dbase + 8] = ((uint4*)tl)[1];
      #pragma unroll
      for (int j = 0; j < 4; ++j)
        *(float4*)&Vs[swzB(lr, dbase + 4 * j)] = vreg[j];
    }
    __syncthreads();                 // staging visible
    if (kt + 1 < 32) {
      int l = (kt + 1) * 64 + lr;
      const float* kro = qkv + ((size_t)(l * kB + b)) * (3 * kE) + kE + h * kHD;
      const float* vro = kro + kE;
      #pragma unroll
      for (int j = 0; j < 4; ++j) {
        kreg[j] = *(const float4*)(kro + dbase + 4 * j);
        vreg[j] = *(const float4*)(vro + dbase + 4 * j);
      }
    }

    // QK^T: split-bf16 MFMA, acc[nf] covers kv cols nf*16+(lane&15)
    f32x4 acc[4];
    #pragma unroll
    for (int nf = 0; nf < 4; ++nf) acc[nf] = (f32x4){0.f, 0.f, 0.f, 0.f};
    #pragma unroll
    for (int ks = 0; ks < 2; ++ks) {
      #pragma unroll
      for (int nf = 0; nf < 4; ++nf) {
        bf16x8 kh = *(const bf16x8*)&Khi[nf * 16 + l15][ks * 32 + l4 * 8];
        bf16x8 kl = *(const bf16x8*)&Klo[nf * 16 + l15][ks * 32 + l4 * 8];
        acc[nf] = __builtin_amdgcn_mfma_f32_16x16x32_bf16(qhi[ks], kh, acc[nf], 0, 0, 0);
        acc[nf] = __builtin_amdgcn_mfma_f32_16x16x32_bf16(qhi[ks], kl, acc[nf], 0, 0, 0);
        acc[nf] = __builtin_amdgcn_mfma_f32_16x16x32_bf16(qlo[ks], kh, acc[nf], 0, 0, 0);
      }
    }

    // softmax in MFMA C-layout: row = w*16 + l4*4 + r, col = nf*16 + l15
    #pragma unroll
    for (int r = 0; r < 4; ++r) {
      float tm = fmaxf(fmaxf(acc[0][r], acc[1][r]), fmaxf(acc[2][r], acc[3][r]));
      #pragma unroll
      for (int m = 1; m < 16; m <<= 1) tm = fmaxf(tm, __shfl_xor(tm, m));
      float mn = fmaxf(m_i[r], tm);
      float alpha = __expf(m_i[r] - mn);
      m_i[r] = mn;
      int qrow = w * 16 + l4 * 4 + r;
      float rs = 0.f;
      #pragma unroll
      for (int nf = 0; nf < 4; ++nf) {
        float p = __expf(acc[nf][r] - mn);
        rs += p;
        Ps[swzB(qrow, nf * 16 + l15)] = p;
      }
      #pragma unroll
      for (int m = 1; m < 16; m <<= 1) rs += __shfl_xor(rs, m);
      l_i[r] = l_i[r] * alpha + rs;
      if (l15 == 0) salpha[qrow] = alpha;
    }
    __syncthreads();                 // P + salpha visible

    // PV in f32 (thread layout ty/tx)
    float al[4];
    #pragma unroll
    for (int i = 0; i < 4; ++i) al[i] = salpha[ty * 4 + i];
    #pragma unroll
    for (int i = 0; i < 4; ++i)
      #pragma unroll
      for (int j = 0; j < 4; ++j) Oa[i][j] *= al[i];
    #pragma unroll 4
    for (int kvc = 0; kvc < 16; ++kvc) {
      float pvw[4][4];
      #pragma unroll
      for (int i = 0; i < 4; ++i)
        *(float4*)&pvw[i][0] = *(const float4*)&Ps[swzB(ty * 4 + i, kvc * 4)];
      #pragma unroll
      for (int q = 0; q < 4; ++q) {
        float4 vv = *(const float4*)&Vs[swzB(kvc * 4 + q, tx * 4)];
        float va[4] = {vv.x, vv.y, vv.z, vv.w};
        #pragma unroll
        for (int i = 0; i < 4; ++i)
          #pragma unroll
          for (int j = 0; j < 4; ++j)
            Oa[i][j] = fmaf(pvw[i][q], va[j], Oa[i][j]);
      }
    }
  }

  // final denominators: bridge softmax-layout l_i to PV layout
  if (l15 == 0) {
    #pragma unroll
    for (int r = 0; r < 4; ++r) sli[w * 16 + l4 * 4 + r] = l_i[r];
  }
  __syncthreads();
  #pragma unroll
  for (int i = 0; i < 4; ++i) {
    int l = qt * 64 + ty * 4 + i;
    float inv = 1.0f / sli[ty * 4 + i];
    float4 o = make_float4(Oa[i][0]*inv, Oa[i][1]*inv, Oa[i][2]*inv, Oa[i][3]*inv);
    *(float4*)(attn_out + ((size_t)(l * kB + b)) * kE + h * kHD + tx * 4) = o;
  }
}

// ---------------- Gating: logits, softmax, top2, partitionable-XOR threefry --
__global__ __launch_bounds__(256) void gating_kernel(
    const float* __restrict__ h2, const float* __restrict__ wg,
    int* __restrict__ e1, int* __restrict__ e2,
    float* __restrict__ g1, float* __restrict__ g2,
    int* __restrict__ keepr) {
  __shared__ float swg[kE * kNE];
  for (int i = threadIdx.x; i < kE * kNE; i += 256) swg[i] = wg[i];
  __syncthreads();
  int w = threadIdx.x >> 6, lane = threadIdx.x & 63;
  int tok = blockIdx.x * 4 + w;
  const float* xr = h2 + (size_t)tok * kE;
  float a0=0,a1=0,a2=0,a3=0,a4=0;
  for (int d = lane; d < kE; d += 64) {
    float xv = xr[d];
    a0 = fmaf(xv, swg[d*5+0], a0);
    a1 = fmaf(xv, swg[d*5+1], a1);
    a2 = fmaf(xv, swg[d*5+2], a2);
    a3 = fmaf(xv, swg[d*5+3], a3);
    a4 = fmaf(xv, swg[d*5+4], a4);
  }
  #pragma unroll
  for (int m = 32; m; m >>= 1) {
    a0 += __shfl_xor(a0, m); a1 += __shfl_xor(a1, m); a2 += __shfl_xor(a2, m);
    a3 += __shfl_xor(a3, m); a4 += __shfl_xor(a4, m);
  }
  if (lane == 0) {
    float lg[5] = {a0, a1, a2, a3, a4};
    float mx = lg[0];
    #pragma unroll
    for (int e = 1; e < 5; ++e) mx = fmaxf(mx, lg[e]);
    float ex[5], ssum = 0.f;
    #pragma unroll
    for (int e = 0; e < 5; ++e) { ex[e] = expf(lg[e] - mx); ssum += ex[e]; }
    float raw[5];
    #pragma unroll
    for (int e = 0; e < 5; ++e) raw[e] = ex[e] / ssum;
    int i1 = 0; float v1 = raw[0];
    #pragma unroll
    for (int e = 1; e < 5; ++e) if (raw[e] > v1) { v1 = raw[e]; i1 = e; }
    int i2 = 0; float v2 = -1.f;
    #pragma unroll
    for (int e = 0; e < 5; ++e) if (e != i1 && raw[e] > v2) { v2 = raw[e]; i2 = e; }
    float denom = v1 + v2 + 1e-9f;
    float G1 = v1 / denom, G2 = v2 / denom;
    unsigned x0 = 0u, x1 = (unsigned)tok;
    threefry(x0, x1);
    unsigned bits = x0 ^ x1;
    float u = __uint_as_float((bits >> 9) | 0x3F800000u) - 1.0f;
    int kr = (u < G2 / 0.2f) ? 1 : 0;
    e1[tok] = i1; e2[tok] = i2; g1[tok] = G1; g2[tok] = G2; keepr[tok] = kr;
  }
}

// ---------------- Per-group plan: positions + capacity -----------------------
__global__ __launch_bounds__(256) void plan_kernel(
    const int* __restrict__ e1, const int* __restrict__ e2,
    const int* __restrict__ keepr,
    int* __restrict__ slot1, int* __restrict__ slot2, int* __restrict__ tot) {
  int l = blockIdx.x * blockDim.x + threadIdx.x;
  if (l >= kL) return;
  int base = l * 4;
  int e1v[4], e2v[4], kr[4];
  #pragma unroll
  for (int n = 0; n < 4; ++n) {
    e1v[n] = e1[base + n]; e2v[n] = e2[base + n]; kr[n] = keepr[base + n];
  }
  int c1[5] = {0,0,0,0,0};
  int s1[4];
  #pragma unroll
  for (int n = 0; n < 4; ++n) {
    int e = e1v[n];
    int p = 0;
    #pragma unroll
    for (int q = 0; q < 5; ++q) if (q == e) p = c1[q];
    s1[n] = p;
    #pragma unroll
    for (int q = 0; q < 5; ++q) c1[q] += (q == e);
  }
  int run[5] = {0,0,0,0,0};
  int s2[4];
  #pragma unroll
  for (int n = 0; n < 4; ++n) {
    s2[n] = -1;
    if (kr[n]) {
      int e = e2v[n];
      int p = 0;
      #pragma unroll
      for (int q = 0; q < 5; ++q) if (q == e) p = c1[q] + run[q];
      if (p < kCAP) s2[n] = p;
      #pragma unroll
      for (int q = 0; q < 5; ++q) run[q] += (q == e);
    }
  }
  #pragma unroll
  for (int n = 0; n < 4; ++n) { slot1[base + n] = s1[n]; slot2[base + n] = s2[n]; }
  int adm[5] = {0,0,0,0,0};
  #pragma unroll
  for (int n = 0; n < 4; ++n)
    if (s2[n] >= 0) {
      #pragma unroll
      for (int q = 0; q < 5; ++q) adm[q] += (q == e2v[n]);
    }
  #pragma unroll
  for (int q = 0; q < 5; ++q) tot[l * kNE + q] = c1[q] + adm[q];
}

// ---------------- Per-expert exclusive scan of group totals ------------------
__global__ __launch_bounds__(256) void scan_kernel(
    const int* __restrict__ tot, int* __restrict__ gbase, int* __restrict__ cnt) {
  int e = blockIdx.x;
  int t = threadIdx.x;
  int lane = t & 63, w = t >> 6;
  __shared__ int wsum[4];
  __shared__ int carry;
  if (t == 0) carry = 0;
  __syncthreads();
  for (int chunk = 0; chunk < kL / 256; ++chunk) {
    int g = chunk * 256 + t;
    int v = tot[g * kNE + e];
    int inc = v;
    #pragma unroll
    for (int off = 1; off < 64; off <<= 1) {
      int u = __shfl_up(inc, off);
      if (lane >= off) inc += u;
    }
    if (lane == 63) wsum[w] = inc;
    __syncthreads();
    int wb = 0;
    #pragma unroll
    for (int i = 0; i < 4; ++i) wb += (i < w) ? wsum[i] : 0;
    int total = wsum[0] + wsum[1] + wsum[2] + wsum[3];
    gbase[g * kNE + e] = carry + wb + inc - v;
    __syncthreads();
    if (t == 0) carry += total;
    __syncthreads();
  }
  if (t == 0) cnt[e] = carry;
}

__global__ void bases_kernel(const int* __restrict__ cnt, int* __restrict__ base) {
  if (threadIdx.x == 0 && blockIdx.x == 0) {
    int a = 0;
    #pragma unroll
    for (int e = 0; e < kNE; ++e) { base[e] = a; a += cnt[e]; }
  }
}

// ---------------- Row map: token -> expert-buffer rows -----------------------
__global__ __launch_bounds__(256) void rowmap_kernel(
    const int* __restrict__ e1, const int* __restrict__ e2,
    const int* __restrict__ slot1, const int* __restrict__ slot2,
    const int* __restrict__ gbase, const int* __restrict__ ebase,
    int* __restrict__ rowOf1, int* __restrict__ rowOf2,
    int* __restrict__ tokOfRow) {
  int tok = blockIdx.x * blockDim.x + threadIdx.x;
  if (tok >= kT) return;
  int l = tok >> 2;
  int a = e1[tok];
  int r1 = ebase[a] + gbase[l * kNE + a] + slot1[tok];
  rowOf1[tok] = r1;
  tokOfRow[r1] = tok;
  int s2 = slot2[tok];
  int r2 = -1;
  if (s2 >= 0) {
    int bq = e2[tok];
    r2 = ebase[bq] + gbase[l * kNE + bq] + s2;
    tokOfRow[r2] = tok;
  }
  rowOf2[tok] = r2;
}

// ---------------- Final combine: out = x_res + g1*eo[r1] + g2*eo[r2] ---------
__global__ __launch_bounds__(128) void combine_kernel(
    const float* __restrict__ xres, const unsigned short* __restrict__ eo,
    const float* __restrict__ g1, const float* __restrict__ g2,
    const int* __restrict__ rowOf1, const int* __restrict__ rowOf2,
    float* __restrict__ out) {
  int tok = blockIdx.x;
  int t = threadIdx.x;
  float4 o = *(const float4*)(xres + (size_t)tok * kE + t * 4);
  int p1 = rowOf1[tok];
  float G1 = g1[tok];
  ushort4 a = *(const ushort4*)(eo + (size_t)p1 * kE + t * 4);
  o.x += G1 * bf2f(a.x); o.y += G1 * bf2f(a.y);
  o.z += G1 * bf2f(a.z); o.w += G1 * bf2f(a.w);
  int p2 = rowOf2[tok];
  if (p2 >= 0) {
    float G2 = g2[tok];
    ushort4 c = *(const ushort4*)(eo + (size_t)p2 * kE + t * 4);
    o.x += G2 * bf2f(c.x); o.y += G2 * bf2f(c.y);
    o.z += G2 * bf2f(c.z); o.w += G2 * bf2f(c.w);
  }
  *(float4*)(out + (size_t)tok * kE + t * 4) = o;
}

}  // namespace

extern "C" void kernel_launch(void* const* d_in, const int* in_sizes, int n_in,
                              void* d_out, int out_size, void* d_ws, size_t ws_size,
                              hipStream_t stream) {
  (void)in_sizes; (void)n_in; (void)out_size;
  const float* x    = (const float*)d_in[0];
  const float* ln1w = (const float*)d_in[1];
  const float* ln1b = (const float*)d_in[2];
  const float* ln2w = (const float*)d_in[3];
  const float* ln2b = (const float*)d_in[4];
  const float* wqkv = (const float*)d_in[5];
  const float* bqkv = (const float*)d_in[6];
  const float* wo   = (const float*)d_in[7];
  const float* bo   = (const float*)d_in[8];
  const float* wg   = (const float*)d_in[9];
  const float* w1   = (const float*)d_in[10];
  const float* w2   = (const float*)d_in[11];
  float* out = (float*)d_out;

  if (ws_size < (size_t)135000000) return;
  float* ws   = (float*)d_ws;
  float* xres = ws;
  unsigned short* hmoe = (unsigned short*)(ws + 4194304);
  float* qkv  = ws + 4194304;
  float* h1   = ws + 16777216;
  float* h2   = ws + 20971520;
  unsigned short* eobf = (unsigned short*)(ws + 20971520);
  unsigned short* h2bf = (unsigned short*)(ws + 25165824);
  unsigned short* w1bf = (unsigned short*)(ws + 27262976);
  unsigned short* w2bf = (unsigned short*)(ws + 29884416);
  int* ibuf    = (int*)(ws + 32505856);
  int* e1      = ibuf;
  int* e2      = e1 + kT;
  float* g1f   = (float*)(e2 + kT);
  float* g2f   = g1f + kT;
  int* keepr   = (int*)(g2f + kT);
  int* slot1   = keepr + kT;
  int* slot2   = slot1 + kT;
  int* rowOf1  = slot2 + kT;
  int* rowOf2  = rowOf1 + kT;
  int* tot     = rowOf2 + kT;
  int* gbase   = tot + kL * kNE;
  int* tokOfRow= gbase + kL * kNE;
  int* cnt     = tokOfRow + 2 * kT;
  int* ebase   = cnt + 8;

  // 0. weights -> bf16
  f2bf_kernel<<<5120, 256, 0, stream>>>(w1, w1bf, kNE * kE * kFF / 4);
  f2bf_kernel<<<5120, 256, 0, stream>>>(w2, w2bf, kNE * kFF * kE / 4);
  // 1. h1 = LN1(x)
  ln_kernel<<<kT, 256, 0, stream>>>(x, ln1w, ln1b, h1);
  // 2. qkv = h1 @ Wqkv^T + b
  gemm_kernel<1,0><<<dim3(12, 64, 1), 256, 0, stream>>>(
      h1, wqkv, bqkv, nullptr, qkv, kT, 1536, kE);
  // 3. attention (split-bf16 MFMA QK + f32 PV), writes into h1
  flash_kernel<<<dim3(32, 32, 1), 256, 0, stream>>>(qkv, h1);
  // 4. x_res = x + attn_out @ Wo^T + bo
  gemm_kernel<1,1><<<dim3(4, 64, 1), 256, 0, stream>>>(
      h1, wo, bo, x, xres, kT, kE, kE);
  // 5. h2 = LN2(x_res)
  ln_kernel<<<kT, 256, 0, stream>>>(xres, ln2w, ln2b, h2);
  // 6. gating per token
  gating_kernel<<<kL, 256, 0, stream>>>(h2, wg, e1, e2, g1f, g2f, keepr);
  // 6b. h2 -> bf16
  f2bf_kernel<<<4096, 256, 0, stream>>>(h2, h2bf, kT * kE / 4);
  // 7. per-group plan
  plan_kernel<<<kL / 256, 256, 0, stream>>>(e1, e2, keepr, slot1, slot2, tot);
  // 8. per-expert scan; bases; row maps
  scan_kernel<<<kNE, 256, 0, stream>>>(tot, gbase, cnt);
  bases_kernel<<<1, 32, 0, stream>>>(cnt, ebase);
  rowmap_kernel<<<kT / 256, 256, 0, stream>>>(
      e1, e2, slot1, slot2, gbase, ebase, rowOf1, rowOf2, tokOfRow);
  // 9. hmoe = relu(gather(h2bf) @ w1bf[e])
  moe_mfma_kernel<1,1,kE,kFF><<<dim3(16, 64, kNE), 256, 0, stream>>>(
      h2bf, w1bf, hmoe, tokOfRow, cnt, ebase);
  // 10. eo = hmoe @ w2bf[e]
  moe_mfma_kernel<0,0,kFF,kE><<<dim3(4, 64, kNE), 256, 0, stream>>>(
      hmoe, w2bf, eobf, nullptr, cnt, ebase);
  // 11. out = x_res + g1*eo + g2*eo
  combine_kernel<<<kT, 128, 0, stream>>>(
      xres, eobf, g1f, g2f, rowOf1, rowOf2, out);
}

// Round 14
// 746.914 us; speedup vs baseline: 1.5614x; 1.3165x over previous
//
#include <hip/hip_runtime.h>

#define DI __device__ __forceinline__

namespace {

constexpr int kL  = 2048;
constexpr int kB  = 4;
constexpr int kE  = 512;
constexpr int kHD = 64;
constexpr int kFF = 2048;
constexpr int kNE = 5;
constexpr int kT  = 8192;   // kL * kB tokens
constexpr int kCAP = 4;

using bf16x8 = __attribute__((ext_vector_type(8))) short;
using f32x4  = __attribute__((ext_vector_type(4))) float;

DI float bf2f(unsigned short u) { return __uint_as_float(((unsigned)u) << 16); }
DI unsigned short f2bf(float f) {
  unsigned u = __float_as_uint(f);
  u = u + 0x7FFFu + ((u >> 16) & 1u);
  return (unsigned short)(u >> 16);
}

DI unsigned rotl(unsigned v, int d) { return (v << d) | (v >> (32 - d)); }

// JAX threefry2x32 with key = PRNGKey(42) = (0, 42), 20 rounds.
DI void threefry(unsigned& x0, unsigned& x1) {
  const unsigned K1 = 0u, K2 = 42u, K3 = 0x1BD11BDAu ^ 0u ^ 42u;
  x0 += K1; x1 += K2;
  x0 += x1; x1 = rotl(x1, 13); x1 ^= x0;
  x0 += x1; x1 = rotl(x1, 15); x1 ^= x0;
  x0 += x1; x1 = rotl(x1, 26); x1 ^= x0;
  x0 += x1; x1 = rotl(x1,  6); x1 ^= x0;
  x0 += K2; x1 += K3 + 1u;
  x0 += x1; x1 = rotl(x1, 17); x1 ^= x0;
  x0 += x1; x1 = rotl(x1, 29); x1 ^= x0;
  x0 += x1; x1 = rotl(x1, 16); x1 ^= x0;
  x0 += x1; x1 = rotl(x1, 24); x1 ^= x0;
  x0 += K3; x1 += K1 + 2u;
  x0 += x1; x1 = rotl(x1, 13); x1 ^= x0;
  x0 += x1; x1 = rotl(x1, 15); x1 ^= x0;
  x0 += x1; x1 = rotl(x1, 26); x1 ^= x0;
  x0 += x1; x1 = rotl(x1,  6); x1 ^= x0;
  x0 += K1; x1 += K2 + 3u;
  x0 += x1; x1 = rotl(x1, 17); x1 ^= x0;
  x0 += x1; x1 = rotl(x1, 29); x1 ^= x0;
  x0 += x1; x1 = rotl(x1, 16); x1 ^= x0;
  x0 += x1; x1 = rotl(x1, 24); x1 ^= x0;
  x0 += K2; x1 += K3 + 4u;
  x0 += x1; x1 = rotl(x1, 13); x1 ^= x0;
  x0 += x1; x1 = rotl(x1, 15); x1 ^= x0;
  x0 += x1; x1 = rotl(x1, 26); x1 ^= x0;
  x0 += x1; x1 = rotl(x1,  6); x1 ^= x0;
  x0 += K3; x1 += K1 + 5u;
}

// ---------------- f32 -> bf16 bulk convert -----------------------------------
__global__ __launch_bounds__(256) void f2bf_kernel(
    const float* __restrict__ src, unsigned short* __restrict__ dst, int n4) {
  int i = blockIdx.x * blockDim.x + threadIdx.x;
  if (i >= n4) return;
  float4 v = ((const float4*)src)[i];
  ushort4 u;
  u.x = f2bf(v.x); u.y = f2bf(v.y); u.z = f2bf(v.z); u.w = f2bf(v.w);
  ((ushort4*)dst)[i] = u;
}

// ---------------- LayerNorm (one row per block, 256 threads, E=512) -----------
__global__ __launch_bounds__(256) void ln_kernel(
    const float* __restrict__ x, const float* __restrict__ w,
    const float* __restrict__ b, float* __restrict__ out) {
  int row = blockIdx.x;
  const float* xr = x + (size_t)row * kE;
  int t = threadIdx.x;
  float2 v = *(const float2*)(xr + t * 2);
  __shared__ float red[4];
  float s = v.x + v.y;
  #pragma unroll
  for (int m = 32; m; m >>= 1) s += __shfl_xor(s, m);
  if ((t & 63) == 0) red[t >> 6] = s;
  __syncthreads();
  float mu = (red[0] + red[1] + red[2] + red[3]) * (1.0f / kE);
  float dx = v.x - mu, dy = v.y - mu;
  float q = dx * dx + dy * dy;
  #pragma unroll
  for (int m = 32; m; m >>= 1) q += __shfl_xor(q, m);
  __syncthreads();
  if ((t & 63) == 0) red[t >> 6] = q;
  __syncthreads();
  float var = (red[0] + red[1] + red[2] + red[3]) * (1.0f / kE);
  float inv = 1.0f / sqrtf(var + 1e-5f);
  float2 o;
  o.x = dx * inv * w[t * 2]     + b[t * 2];
  o.y = dy * inv * w[t * 2 + 1] + b[t * 2 + 1];
  *(float2*)(out + (size_t)row * kE + t * 2) = o;
}

// ---------------- 128x128 f32 GEMM, BT=1 (C=A*B^T), non-MOE ------------------
template <int BIAS, int RES>
__global__ __launch_bounds__(256) void gemm_kernel(
    const float* __restrict__ Ap, const float* __restrict__ Bp,
    const float* __restrict__ biasp, const float* __restrict__ Rp,
    float* __restrict__ Cp, int M, int N, int K) {
  __shared__ float As[2][16][132];
  __shared__ float Bs[2][16][132];

  int nwg = gridDim.x * gridDim.y;
  int bid = blockIdx.y * gridDim.x + blockIdx.x;
  int swz = (bid & 7) * (nwg >> 3) + (bid >> 3);
  int wx = swz % gridDim.x, wy = swz / gridDim.x;

  const int m0 = wy * 128;
  const int n0 = wx * 128;
  const int t = threadIdx.x;
  const int tx = t & 15, ty = t >> 4;

  const int ar = t >> 2;
  const int ak = (t & 3) * 4;
  size_t arow0 = (size_t)(m0 + ar) * K + ak;
  size_t arow1 = (size_t)(m0 + ar + 64) * K + ak;
  const int b_r = t >> 2, b_o = (t & 3) * 4;

  float acc[8][8];
  #pragma unroll
  for (int i = 0; i < 8; ++i)
    #pragma unroll
    for (int j = 0; j < 8; ++j) acc[i][j] = 0.0f;

  float4 v0r, v1r, w0, w1v;
  auto load_tile = [&](int k0) {
    v0r = *(const float4*)(Ap + arow0 + k0);
    v1r = *(const float4*)(Ap + arow1 + k0);
    w0  = *(const float4*)(Bp + (size_t)(n0 + b_r) * K + k0 + b_o);
    w1v = *(const float4*)(Bp + (size_t)(n0 + b_r + 64) * K + k0 + b_o);
  };
  load_tile(0);

  for (int k0 = 0; k0 < K; k0 += 16) {
    const int bf = (k0 >> 4) & 1;
    As[bf][ak+0][ar] = v0r.x; As[bf][ak+1][ar] = v0r.y;
    As[bf][ak+2][ar] = v0r.z; As[bf][ak+3][ar] = v0r.w;
    As[bf][ak+0][ar+64] = v1r.x; As[bf][ak+1][ar+64] = v1r.y;
    As[bf][ak+2][ar+64] = v1r.z; As[bf][ak+3][ar+64] = v1r.w;
    Bs[bf][b_o+0][b_r] = w0.x; Bs[bf][b_o+1][b_r] = w0.y;
    Bs[bf][b_o+2][b_r] = w0.z; Bs[bf][b_o+3][b_r] = w0.w;
    Bs[bf][b_o+0][b_r+64] = w1v.x; Bs[bf][b_o+1][b_r+64] = w1v.y;
    Bs[bf][b_o+2][b_r+64] = w1v.z; Bs[bf][b_o+3][b_r+64] = w1v.w;
    __syncthreads();
    if (k0 + 16 < K) load_tile(k0 + 16);
    #pragma unroll
    for (int kk = 0; kk < 16; ++kk) {
      float av[8], bv[8];
      *(float4*)&av[0] = *(const float4*)&As[bf][kk][ty * 8];
      *(float4*)&av[4] = *(const float4*)&As[bf][kk][ty * 8 + 4];
      *(float4*)&bv[0] = *(const float4*)&Bs[bf][kk][tx * 4];
      *(float4*)&bv[4] = *(const float4*)&Bs[bf][kk][tx * 4 + 64];
      #pragma unroll
      for (int i = 0; i < 8; ++i)
        #pragma unroll
        for (int j = 0; j < 8; ++j)
          acc[i][j] = fmaf(av[i], bv[j], acc[i][j]);
    }
  }

  #pragma unroll
  for (int i = 0; i < 8; ++i) {
    int rloc = m0 + ty * 8 + i;
    size_t crow = (size_t)rloc * N;
    #pragma unroll
    for (int half = 0; half < 2; ++half) {
      int c = n0 + half * 64 + tx * 4;
      float v[4];
      #pragma unroll
      for (int j = 0; j < 4; ++j) {
        v[j] = acc[i][half * 4 + j];
        if (BIAS) v[j] += biasp[c + j];
        if (RES)  v[j] += Rp[crow + c + j];
      }
      *(float4*)(Cp + crow + c) = make_float4(v[0], v[1], v[2], v[3]);
    }
  }
}

// ---------------- MoE bf16 MFMA GEMM (unchanged, verified r11) ---------------
template <int GATHER, int RELU, int K, int N>
__global__ __launch_bounds__(256) void moe_mfma_kernel(
    const unsigned short* __restrict__ Abf, const unsigned short* __restrict__ Bbf,
    unsigned short* __restrict__ Cbf,
    const int* __restrict__ gatherp, const int* __restrict__ cntp,
    const int* __restrict__ basep) {
  __shared__ unsigned short As[128][40];
  __shared__ unsigned short Bs[128][40];

  const int e = blockIdx.z;
  const int M = cntp[e];
  const int rowOff = basep[e];
  if ((int)blockIdx.y * 128 >= M) return;
  const unsigned short* Bg = Bbf + (size_t)e * K * N;
  const int m0 = blockIdx.y * 128;
  const int n0 = blockIdx.x * 128;
  const int t = threadIdx.x;
  const int lane = t & 63, w = t >> 6;
  const int wm = w >> 1, wn = w & 1;

  const int ar = t >> 1, ah = t & 1;
  size_t abase;
  {
    int r = m0 + ar;
    int mm = M - 1; r = r < mm ? r : mm;
    if (GATHER) r = gatherp[rowOff + r];
    else        r += rowOff;
    abase = (size_t)r * K;
  }
  const int bk = t >> 3, bn = (t & 7) * 16;

  f32x4 acc[4][4];
  #pragma unroll
  for (int i = 0; i < 4; ++i)
    #pragma unroll
    for (int j = 0; j < 4; ++j)
      acc[i][j] = (f32x4){0.f, 0.f, 0.f, 0.f};

  uint4 aR0, aR1, bR0, bR1;
  auto gload = [&](int k0) {
    aR0 = *(const uint4*)(Abf + abase + k0 + ah * 16);
    aR1 = *(const uint4*)(Abf + abase + k0 + ah * 16 + 8);
    bR0 = *(const uint4*)(Bg + (size_t)(k0 + bk) * N + n0 + bn);
    bR1 = *(const uint4*)(Bg + (size_t)(k0 + bk) * N + n0 + bn + 8);
  };
  gload(0);

  const int kg = (lane >> 4) * 8;
  const int mr = lane & 15;

  for (int k0 = 0; k0 < K; k0 += 32) {
    __syncthreads();
    *(uint4*)&As[ar][ah * 16]     = aR0;
    *(uint4*)&As[ar][ah * 16 + 8] = aR1;
    {
      unsigned short tmp[16];
      *(uint4*)tmp       = bR0;
      *(uint4*)(tmp + 8) = bR1;
      #pragma unroll
      for (int j = 0; j < 16; ++j) Bs[bn + j][bk] = tmp[j];
    }
    __syncthreads();
    if (k0 + 32 < K) gload(k0 + 32);

    bf16x8 af[4], bfr[4];
    #pragma unroll
    for (int i = 0; i < 4; ++i)
      af[i] = *(const bf16x8*)&As[wm * 64 + i * 16 + mr][kg];
    #pragma unroll
    for (int j = 0; j < 4; ++j)
      bfr[j] = *(const bf16x8*)&Bs[wn * 64 + j * 16 + mr][kg];
    #pragma unroll
    for (int i = 0; i < 4; ++i)
      #pragma unroll
      for (int j = 0; j < 4; ++j)
        acc[i][j] = __builtin_amdgcn_mfma_f32_16x16x32_bf16(
            af[i], bfr[j], acc[i][j], 0, 0, 0);
  }

  const int lr4 = (lane >> 4) * 4;
  const int lc = lane & 15;
  #pragma unroll
  for (int i = 0; i < 4; ++i)
    #pragma unroll
    for (int r = 0; r < 4; ++r) {
      int row = m0 + wm * 64 + i * 16 + lr4 + r;
      if (row >= M) continue;
      size_t crow = (size_t)(row + rowOff) * N;
      #pragma unroll
      for (int j = 0; j < 4; ++j) {
        float v = acc[i][j][r];
        if (RELU) v = v > 0.f ? v : 0.f;
        Cbf[crow + n0 + wn * 64 + j * 16 + lc] = f2bf(v);
      }
    }
}

// ---------------- Flash attention: full split-bf16 MFMA (QK^T and PV) --------
// K staged hi/lo bf16 [64][72]; V staged TRANSPOSED hi/lo [d][kv].
// P (softmax out) aliases the K buffers after QK reads (4 barriers/tile).
// LDS = 4 x 9216B = 36.9 KB -> 4 blocks/CU. XOR swizzle (8-aligned) on the
// k-index per row for bank spread; preserves bf16x8 contiguity/alignment.
DI int pswz(int row) { return ((row >> 1) & 7) << 3; }

__global__ __launch_bounds__(256) void flash_kernel(
    const float* __restrict__ qkv, float* __restrict__ attn_out) {
  __shared__ unsigned short KPhi[64][72];   // K during QK; P during PV
  __shared__ unsigned short KPlo[64][72];
  __shared__ unsigned short Vthi[64][72];   // V^T: [d][kv]
  __shared__ unsigned short Vtlo[64][72];

  int bid = blockIdx.y * 32 + blockIdx.x;   // grid (32, 32)
  int swzb = (bid & 7) * 128 + (bid >> 3);
  const int bh = swzb >> 5;
  const int qt = swzb & 31;
  const int b = bh >> 3, h = bh & 7;
  const int t = threadIdx.x;
  const int w = t >> 6, lane = t & 63;
  const int l15 = lane & 15, l4 = lane >> 4;
  const int lr = t >> 2;             // K-staging row 0..63
  const int dbase = (t & 3) * 16;    // K-staging d offset
  const int vd = t & 63;             // V-staging column (d)
  const int kv0 = (t >> 6) * 16;     // V-staging kv block

  // Q A-fragments in registers, scaled 0.125, split hi/lo
  bf16x8 qhi[2], qlo[2];
  {
    int qglob = qt * 64 + w * 16 + l15;
    const float* qrow = qkv + ((size_t)(qglob * kB + b)) * (3 * kE) + h * kHD;
    #pragma unroll
    for (int ks = 0; ks < 2; ++ks) {
      int d0 = ks * 32 + l4 * 8;
      float4 v0 = *(const float4*)(qrow + d0);
      float4 v1 = *(const float4*)(qrow + d0 + 4);
      float vv[8] = {v0.x, v0.y, v0.z, v0.w, v1.x, v1.y, v1.z, v1.w};
      #pragma unroll
      for (int i = 0; i < 8; ++i) {
        float xq = vv[i] * 0.125f;
        unsigned short hi = f2bf(xq);
        qhi[ks][i] = (short)hi;
        qlo[ks][i] = (short)f2bf(xq - bf2f(hi));
      }
    }
  }

  float m_i[4], l_i[4];
  f32x4 Oacc[4];                     // [df]; element r -> q-row w*16+l4*4+r
  #pragma unroll
  for (int r = 0; r < 4; ++r) { m_i[r] = -1e30f; l_i[r] = 0.f; }
  #pragma unroll
  for (int df = 0; df < 4; ++df) Oacc[df] = (f32x4){0.f, 0.f, 0.f, 0.f};

  float kreg[16], vreg[16];
  {
    const float* kro = qkv + ((size_t)(lr * kB + b)) * (3 * kE) + kE + h * kHD;
    #pragma unroll
    for (int j = 0; j < 4; ++j)
      *(float4*)&kreg[j * 4] = *(const float4*)(kro + dbase + 4 * j);
    #pragma unroll
    for (int j = 0; j < 16; ++j)
      vreg[j] = qkv[((size_t)((kv0 + j) * kB + b)) * (3 * kE) + 2 * kE + h * kHD + vd];
  }

  for (int kt = 0; kt < 32; ++kt) {
    __syncthreads();                 // barA: prev tile's PV reads done
    {
      unsigned short th[16], tl[16];
      #pragma unroll
      for (int i = 0; i < 16; ++i) {
        unsigned short hi = f2bf(kreg[i]);
        th[i] = hi; tl[i] = f2bf(kreg[i] - bf2f(hi));
      }
      int sw = pswz(lr);
      *(uint4*)&KPhi[lr][(dbase)     ^ sw] = ((uint4*)th)[0];
      *(uint4*)&KPhi[lr][(dbase + 8) ^ sw] = ((uint4*)th)[1];
      *(uint4*)&KPlo[lr][(dbase)     ^ sw] = ((uint4*)tl)[0];
      *(uint4*)&KPlo[lr][(dbase + 8) ^ sw] = ((uint4*)tl)[1];
      #pragma unroll
      for (int i = 0; i < 16; ++i) {
        unsigned short hi = f2bf(vreg[i]);
        th[i] = hi; tl[i] = f2bf(vreg[i] - bf2f(hi));
      }
      int swv = pswz(vd);
      *(uint4*)&Vthi[vd][(kv0)     ^ swv] = ((uint4*)th)[0];
      *(uint4*)&Vthi[vd][(kv0 + 8) ^ swv] = ((uint4*)th)[1];
      *(uint4*)&Vtlo[vd][(kv0)     ^ swv] = ((uint4*)tl)[0];
      *(uint4*)&Vtlo[vd][(kv0 + 8) ^ swv] = ((uint4*)tl)[1];
    }
    __syncthreads();                 // barB: K/V staged
    if (kt + 1 < 32) {
      int l = (kt + 1) * 64;
      const float* kro = qkv + ((size_t)((l + lr) * kB + b)) * (3 * kE) + kE + h * kHD;
      #pragma unroll
      for (int j = 0; j < 4; ++j)
        *(float4*)&kreg[j * 4] = *(const float4*)(kro + dbase + 4 * j);
      #pragma unroll
      for (int j = 0; j < 16; ++j)
        vreg[j] = qkv[((size_t)((l + kv0 + j) * kB + b)) * (3 * kE) + 2 * kE + h * kHD + vd];
    }

    // QK^T: split-bf16 MFMA; acc[nf] -> kv cols nf*16+l15, q rows l4*4+r
    f32x4 acc[4];
    #pragma unroll
    for (int nf = 0; nf < 4; ++nf) acc[nf] = (f32x4){0.f, 0.f, 0.f, 0.f};
    #pragma unroll
    for (int ks = 0; ks < 2; ++ks) {
      #pragma unroll
      for (int nf = 0; nf < 4; ++nf) {
        int krow = nf * 16 + l15;
        int off = (ks * 32 + l4 * 8) ^ pswz(krow);
        bf16x8 kh = *(const bf16x8*)&KPhi[krow][off];
        bf16x8 kl = *(const bf16x8*)&KPlo[krow][off];
        acc[nf] = __builtin_amdgcn_mfma_f32_16x16x32_bf16(qhi[ks], kh, acc[nf], 0, 0, 0);
        acc[nf] = __builtin_amdgcn_mfma_f32_16x16x32_bf16(qhi[ks], kl, acc[nf], 0, 0, 0);
        acc[nf] = __builtin_amdgcn_mfma_f32_16x16x32_bf16(qlo[ks], kh, acc[nf], 0, 0, 0);
      }
    }

    // online softmax in C-layout; O-rescale is lane-local (same row mapping)
    float pv[4][4];
    float alpha[4];
    #pragma unroll
    for (int r = 0; r < 4; ++r) {
      float tm = fmaxf(fmaxf(acc[0][r], acc[1][r]), fmaxf(acc[2][r], acc[3][r]));
      #pragma unroll
      for (int m = 1; m < 16; m <<= 1) tm = fmaxf(tm, __shfl_xor(tm, m));
      float mn = fmaxf(m_i[r], tm);
      alpha[r] = __expf(m_i[r] - mn);
      m_i[r] = mn;
      float rs = 0.f;
      #pragma unroll
      for (int nf = 0; nf < 4; ++nf) {
        float p = __expf(acc[nf][r] - mn);
        pv[r][nf] = p;
        rs += p;
      }
      #pragma unroll
      for (int m = 1; m < 16; m <<= 1) rs += __shfl_xor(rs, m);
      l_i[r] = l_i[r] * alpha[r] + rs;
    }
    #pragma unroll
    for (int df = 0; df < 4; ++df)
      #pragma unroll
      for (int r = 0; r < 4; ++r) Oacc[df][r] *= alpha[r];

    __syncthreads();                 // barC: K reads done; buffers free for P
    #pragma unroll
    for (int r = 0; r < 4; ++r) {
      int qrow = w * 16 + l4 * 4 + r;
      int sw = pswz(qrow);
      #pragma unroll
      for (int nf = 0; nf < 4; ++nf) {
        int scol = (nf * 16 + l15) ^ sw;
        float p = pv[r][nf];
        unsigned short hi = f2bf(p);
        KPhi[qrow][scol] = hi;
        KPlo[qrow][scol] = f2bf(p - bf2f(hi));
      }
    }
    __syncthreads();                 // barD: P visible

    // PV: split-bf16 MFMA; A = P [qrow][kv], B = V^T [d][kv]
    {
      int prow = w * 16 + l15;
      int swp = pswz(prow);
      #pragma unroll
      for (int ks = 0; ks < 2; ++ks) {
        int koff = ks * 32 + l4 * 8;
        bf16x8 ph = *(const bf16x8*)&KPhi[prow][koff ^ swp];
        bf16x8 pl = *(const bf16x8*)&KPlo[prow][koff ^ swp];
        #pragma unroll
        for (int df = 0; df < 4; ++df) {
          int vrow = df * 16 + l15;
          int off = koff ^ pswz(vrow);
          bf16x8 vh = *(const bf16x8*)&Vthi[vrow][off];
          bf16x8 vl = *(const bf16x8*)&Vtlo[vrow][off];
          Oacc[df] = __builtin_amdgcn_mfma_f32_16x16x32_bf16(ph, vh, Oacc[df], 0, 0, 0);
          Oacc[df] = __builtin_amdgcn_mfma_f32_16x16x32_bf16(ph, vl, Oacc[df], 0, 0, 0);
          Oacc[df] = __builtin_amdgcn_mfma_f32_16x16x32_bf16(pl, vh, Oacc[df], 0, 0, 0);
        }
      }
    }
  }

  // output: row = qt*64 + w*16 + l4*4 + r, col = h*64 + df*16 + l15
  #pragma unroll
  for (int r = 0; r < 4; ++r) {
    float inv = 1.0f / l_i[r];
    int l = qt * 64 + w * 16 + l4 * 4 + r;
    float* orow = attn_out + ((size_t)(l * kB + b)) * kE + h * kHD;
    #pragma unroll
    for (int df = 0; df < 4; ++df)
      orow[df * 16 + l15] = Oacc[df][r] * inv;
  }
}

// ---------------- Gating: logits, softmax, top2, partitionable-XOR threefry --
__global__ __launch_bounds__(256) void gating_kernel(
    const float* __restrict__ h2, const float* __restrict__ wg,
    int* __restrict__ e1, int* __restrict__ e2,
    float* __restrict__ g1, float* __restrict__ g2,
    int* __restrict__ keepr) {
  __shared__ float swg[kE * kNE];
  for (int i = threadIdx.x; i < kE * kNE; i += 256) swg[i] = wg[i];
  __syncthreads();
  int w = threadIdx.x >> 6, lane = threadIdx.x & 63;
  int tok = blockIdx.x * 4 + w;
  const float* xr = h2 + (size_t)tok * kE;
  float a0=0,a1=0,a2=0,a3=0,a4=0;
  for (int d = lane; d < kE; d += 64) {
    float xv = xr[d];
    a0 = fmaf(xv, swg[d*5+0], a0);
    a1 = fmaf(xv, swg[d*5+1], a1);
    a2 = fmaf(xv, swg[d*5+2], a2);
    a3 = fmaf(xv, swg[d*5+3], a3);
    a4 = fmaf(xv, swg[d*5+4], a4);
  }
  #pragma unroll
  for (int m = 32; m; m >>= 1) {
    a0 += __shfl_xor(a0, m); a1 += __shfl_xor(a1, m); a2 += __shfl_xor(a2, m);
    a3 += __shfl_xor(a3, m); a4 += __shfl_xor(a4, m);
  }
  if (lane == 0) {
    float lg[5] = {a0, a1, a2, a3, a4};
    float mx = lg[0];
    #pragma unroll
    for (int e = 1; e < 5; ++e) mx = fmaxf(mx, lg[e]);
    float ex[5], ssum = 0.f;
    #pragma unroll
    for (int e = 0; e < 5; ++e) { ex[e] = expf(lg[e] - mx); ssum += ex[e]; }
    float raw[5];
    #pragma unroll
    for (int e = 0; e < 5; ++e) raw[e] = ex[e] / ssum;
    int i1 = 0; float v1 = raw[0];
    #pragma unroll
    for (int e = 1; e < 5; ++e) if (raw[e] > v1) { v1 = raw[e]; i1 = e; }
    int i2 = 0; float v2 = -1.f;
    #pragma unroll
    for (int e = 0; e < 5; ++e) if (e != i1 && raw[e] > v2) { v2 = raw[e]; i2 = e; }
    float denom = v1 + v2 + 1e-9f;
    float G1 = v1 / denom, G2 = v2 / denom;
    unsigned x0 = 0u, x1 = (unsigned)tok;
    threefry(x0, x1);
    unsigned bits = x0 ^ x1;
    float u = __uint_as_float((bits >> 9) | 0x3F800000u) - 1.0f;
    int kr = (u < G2 / 0.2f) ? 1 : 0;
    e1[tok] = i1; e2[tok] = i2; g1[tok] = G1; g2[tok] = G2; keepr[tok] = kr;
  }
}

// ---------------- Per-group plan: positions + capacity -----------------------
__global__ __launch_bounds__(256) void plan_kernel(
    const int* __restrict__ e1, const int* __restrict__ e2,
    const int* __restrict__ keepr,
    int* __restrict__ slot1, int* __restrict__ slot2, int* __restrict__ tot) {
  int l = blockIdx.x * blockDim.x + threadIdx.x;
  if (l >= kL) return;
  int base = l * 4;
  int e1v[4], e2v[4], kr[4];
  #pragma unroll
  for (int n = 0; n < 4; ++n) {
    e1v[n] = e1[base + n]; e2v[n] = e2[base + n]; kr[n] = keepr[base + n];
  }
  int c1[5] = {0,0,0,0,0};
  int s1[4];
  #pragma unroll
  for (int n = 0; n < 4; ++n) {
    int e = e1v[n];
    int p = 0;
    #pragma unroll
    for (int q = 0; q < 5; ++q) if (q == e) p = c1[q];
    s1[n] = p;
    #pragma unroll
    for (int q = 0; q < 5; ++q) c1[q] += (q == e);
  }
  int run[5] = {0,0,0,0,0};
  int s2[4];
  #pragma unroll
  for (int n = 0; n < 4; ++n) {
    s2[n] = -1;
    if (kr[n]) {
      int e = e2v[n];
      int p = 0;
      #pragma unroll
      for (int q = 0; q < 5; ++q) if (q == e) p = c1[q] + run[q];
      if (p < kCAP) s2[n] = p;
      #pragma unroll
      for (int q = 0; q < 5; ++q) run[q] += (q == e);
    }
  }
  #pragma unroll
  for (int n = 0; n < 4; ++n) { slot1[base + n] = s1[n]; slot2[base + n] = s2[n]; }
  int adm[5] = {0,0,0,0,0};
  #pragma unroll
  for (int n = 0; n < 4; ++n)
    if (s2[n] >= 0) {
      #pragma unroll
      for (int q = 0; q < 5; ++q) adm[q] += (q == e2v[n]);
    }
  #pragma unroll
  for (int q = 0; q < 5; ++q) tot[l * kNE + q] = c1[q] + adm[q];
}

// ---------------- Per-expert exclusive scan of group totals ------------------
__global__ __launch_bounds__(256) void scan_kernel(
    const int* __restrict__ tot, int* __restrict__ gbase, int* __restrict__ cnt) {
  int e = blockIdx.x;
  int t = threadIdx.x;
  int lane = t & 63, w = t >> 6;
  __shared__ int wsum[4];
  __shared__ int carry;
  if (t == 0) carry = 0;
  __syncthreads();
  for (int chunk = 0; chunk < kL / 256; ++chunk) {
    int g = chunk * 256 + t;
    int v = tot[g * kNE + e];
    int inc = v;
    #pragma unroll
    for (int off = 1; off < 64; off <<= 1) {
      int u = __shfl_up(inc, off);
      if (lane >= off) inc += u;
    }
    if (lane == 63) wsum[w] = inc;
    __syncthreads();
    int wb = 0;
    #pragma unroll
    for (int i = 0; i < 4; ++i) wb += (i < w) ? wsum[i] : 0;
    int total = wsum[0] + wsum[1] + wsum[2] + wsum[3];
    gbase[g * kNE + e] = carry + wb + inc - v;
    __syncthreads();
    if (t == 0) carry += total;
    __syncthreads();
  }
  if (t == 0) cnt[e] = carry;
}

__global__ void bases_kernel(const int* __restrict__ cnt, int* __restrict__ base) {
  if (threadIdx.x == 0 && blockIdx.x == 0) {
    int a = 0;
    #pragma unroll
    for (int e = 0; e < kNE; ++e) { base[e] = a; a += cnt[e]; }
  }
}

// ---------------- Row map: token -> expert-buffer rows -----------------------
__global__ __launch_bounds__(256) void rowmap_kernel(
    const int* __restrict__ e1, const int* __restrict__ e2,
    const int* __restrict__ slot1, const int* __restrict__ slot2,
    const int* __restrict__ gbase, const int* __restrict__ ebase,
    int* __restrict__ rowOf1, int* __restrict__ rowOf2,
    int* __restrict__ tokOfRow) {
  int tok = blockIdx.x * blockDim.x + threadIdx.x;
  if (tok >= kT) return;
  int l = tok >> 2;
  int a = e1[tok];
  int r1 = ebase[a] + gbase[l * kNE + a] + slot1[tok];
  rowOf1[tok] = r1;
  tokOfRow[r1] = tok;
  int s2 = slot2[tok];
  int r2 = -1;
  if (s2 >= 0) {
    int bq = e2[tok];
    r2 = ebase[bq] + gbase[l * kNE + bq] + s2;
    tokOfRow[r2] = tok;
  }
  rowOf2[tok] = r2;
}

// ---------------- Final combine: out = x_res + g1*eo[r1] + g2*eo[r2] ---------
__global__ __launch_bounds__(128) void combine_kernel(
    const float* __restrict__ xres, const unsigned short* __restrict__ eo,
    const float* __restrict__ g1, const float* __restrict__ g2,
    const int* __restrict__ rowOf1, const int* __restrict__ rowOf2,
    float* __restrict__ out) {
  int tok = blockIdx.x;
  int t = threadIdx.x;
  float4 o = *(const float4*)(xres + (size_t)tok * kE + t * 4);
  int p1 = rowOf1[tok];
  float G1 = g1[tok];
  ushort4 a = *(const ushort4*)(eo + (size_t)p1 * kE + t * 4);
  o.x += G1 * bf2f(a.x); o.y += G1 * bf2f(a.y);
  o.z += G1 * bf2f(a.z); o.w += G1 * bf2f(a.w);
  int p2 = rowOf2[tok];
  if (p2 >= 0) {
    float G2 = g2[tok];
    ushort4 c = *(const ushort4*)(eo + (size_t)p2 * kE + t * 4);
    o.x += G2 * bf2f(c.x); o.y += G2 * bf2f(c.y);
    o.z += G2 * bf2f(c.z); o.w += G2 * bf2f(c.w);
  }
  *(float4*)(out + (size_t)tok * kE + t * 4) = o;
}

}  // namespace

extern "C" void kernel_launch(void* const* d_in, const int* in_sizes, int n_in,
                              void* d_out, int out_size, void* d_ws, size_t ws_size,
                              hipStream_t stream) {
  (void)in_sizes; (void)n_in; (void)out_size;
  const float* x    = (const float*)d_in[0];
  const float* ln1w = (const float*)d_in[1];
  const float* ln1b = (const float*)d_in[2];
  const float* ln2w = (const float*)d_in[3];
  const float* ln2b = (const float*)d_in[4];
  const float* wqkv = (const float*)d_in[5];
  const float* bqkv = (const float*)d_in[6];
  const float* wo   = (const float*)d_in[7];
  const float* bo   = (const float*)d_in[8];
  const float* wg   = (const float*)d_in[9];
  const float* w1   = (const float*)d_in[10];
  const float* w2   = (const float*)d_in[11];
  float* out = (float*)d_out;

  if (ws_size < (size_t)135000000) return;
  float* ws   = (float*)d_ws;
  float* xres = ws;
  unsigned short* hmoe = (unsigned short*)(ws + 4194304);
  float* qkv  = ws + 4194304;
  float* h1   = ws + 16777216;
  float* h2   = ws + 20971520;
  unsigned short* eobf = (unsigned short*)(ws + 20971520);
  unsigned short* h2bf = (unsigned short*)(ws + 25165824);
  unsigned short* w1bf = (unsigned short*)(ws + 27262976);
  unsigned short* w2bf = (unsigned short*)(ws + 29884416);
  int* ibuf    = (int*)(ws + 32505856);
  int* e1      = ibuf;
  int* e2      = e1 + kT;
  float* g1f   = (float*)(e2 + kT);
  float* g2f   = g1f + kT;
  int* keepr   = (int*)(g2f + kT);
  int* slot1   = keepr + kT;
  int* slot2   = slot1 + kT;
  int* rowOf1  = slot2 + kT;
  int* rowOf2  = rowOf1 + kT;
  int* tot     = rowOf2 + kT;
  int* gbase   = tot + kL * kNE;
  int* tokOfRow= gbase + kL * kNE;
  int* cnt     = tokOfRow + 2 * kT;
  int* ebase   = cnt + 8;

  // 0. weights -> bf16
  f2bf_kernel<<<5120, 256, 0, stream>>>(w1, w1bf, kNE * kE * kFF / 4);
  f2bf_kernel<<<5120, 256, 0, stream>>>(w2, w2bf, kNE * kFF * kE / 4);
  // 1. h1 = LN1(x)
  ln_kernel<<<kT, 256, 0, stream>>>(x, ln1w, ln1b, h1);
  // 2. qkv = h1 @ Wqkv^T + b
  gemm_kernel<1,0><<<dim3(12, 64, 1), 256, 0, stream>>>(
      h1, wqkv, bqkv, nullptr, qkv, kT, 1536, kE);
  // 3. attention (split-bf16 MFMA QK^T and PV), writes into h1
  flash_kernel<<<dim3(32, 32, 1), 256, 0, stream>>>(qkv, h1);
  // 4. x_res = x + attn_out @ Wo^T + bo
  gemm_kernel<1,1><<<dim3(4, 64, 1), 256, 0, stream>>>(
      h1, wo, bo, x, xres, kT, kE, kE);
  // 5. h2 = LN2(x_res)
  ln_kernel<<<kT, 256, 0, stream>>>(xres, ln2w, ln2b, h2);
  // 6. gating per token
  gating_kernel<<<kL, 256, 0, stream>>>(h2, wg, e1, e2, g1f, g2f, keepr);
  // 6b. h2 -> bf16
  f2bf_kernel<<<4096, 256, 0, stream>>>(h2, h2bf, kT * kE / 4);
  // 7. per-group plan
  plan_kernel<<<kL / 256, 256, 0, stream>>>(e1, e2, keepr, slot1, slot2, tot);
  // 8. per-expert scan; bases; row maps
  scan_kernel<<<kNE, 256, 0, stream>>>(tot, gbase, cnt);
  bases_kernel<<<1, 32, 0, stream>>>(cnt, ebase);
  rowmap_kernel<<<kT / 256, 256, 0, stream>>>(
      e1, e2, slot1, slot2, gbase, ebase, rowOf1, rowOf2, tokOfRow);
  // 9. hmoe = relu(gather(h2bf) @ w1bf[e])
  moe_mfma_kernel<1,1,kE,kFF><<<dim3(16, 64, kNE), 256, 0, stream>>>(
      h2bf, w1bf, hmoe, tokOfRow, cnt, ebase);
  // 10. eo = hmoe @ w2bf[e]
  moe_mfma_kernel<0,0,kFF,kE><<<dim3(4, 64, kNE), 256, 0, stream>>>(
      hmoe, w2bf, eobf, nullptr, cnt, ebase);
  // 11. out = x_res + g1*eo + g2*eo
  combine_kernel<<<kT, 128, 0, stream>>>(
      xres, eobf, g1f, g2f, rowOf1, rowOf2, out);
}